// Round 10
// baseline (514.530 us; speedup 1.0000x reference)
//
#include <hip/hip_runtime.h>

#define B_ 32
#define T_ 4096
#define C_ 256
#define R_ (B_*T_)
#define H1_ 128
#define H2_ 64

#define TB 64   // timestep rows per block in kernel 1

// output layout (floats), concatenated in reference return order
#define PROBS_OFF 0
#define TS_OFF  (R_*4)
#define SEG_OFF (TS_OFF + R_)
#define MI_OFF  (SEG_OFF + R_)
#define MC_OFF  (MI_OFF + R_)

// LDS: only H1 [64][132] = 8448 floats = 33.8 KB -> 3 blocks/CU.
#define H1S_P   132
#define SMEMF   (64 * H1S_P)

__device__ __forceinline__ void fma4(float4& a, float s, const float4& b) {
  a.x = fmaf(s, b.x, a.x); a.y = fmaf(s, b.y, a.y);
  a.z = fmaf(s, b.z, a.z); a.w = fmaf(s, b.w, a.w);
}

__global__ __launch_bounds__(256, 3) void mlp_conv_kernel(
    const float* __restrict__ X, const float* __restrict__ W1, const float* __restrict__ b1,
    const float* __restrict__ W2, const float* __restrict__ b2,
    const float* __restrict__ W3, const float* __restrict__ b3,
    const float* __restrict__ CW, const float* __restrict__ CB,
    float* __restrict__ out)
{
  __shared__ float sm[SMEMF];
  const int tid  = threadIdx.x;
  const int l    = tid & 63;
  const int w    = tid >> 6;
  const int row0 = blockIdx.x * TB;

  // ---- conv1d (C->1, k=3, SAME) + sigmoid, straight from global (L1-backed).
  //      Identical per-row arithmetic to R8 (bit-identical ts). ----
  #pragma unroll
  for (int half = 0; half < 2; ++half) {
    const int rowi = half * 32 + w * 8 + (l & 7);
    const int p = l >> 3;                        // 0..7
    const int grow = row0 + rowi;
    const int tb = grow & (T_ - 1);              // t within its batch row
    const float* x0p = X + (size_t)grow * C_;
    float s = 0.f;
    #pragma unroll
    for (int cc = 0; cc < 8; ++cc) {
      const int c = p * 32 + cc * 4;
      float4 x0 = *(const float4*)&x0p[c];
      float4 xm, xp;
      if (tb == 0)        xm = make_float4(0.f, 0.f, 0.f, 0.f);
      else                xm = *(const float4*)&x0p[c - C_];
      if (tb == T_ - 1)   xp = make_float4(0.f, 0.f, 0.f, 0.f);
      else                xp = *(const float4*)&x0p[c + C_];
      // conv_w flat layout: [c][k], k=0->x[t-1], 1->x[t], 2->x[t+1]
      float4 wa = *(const float4*)&CW[c * 3 + 0];
      float4 wb = *(const float4*)&CW[c * 3 + 4];
      float4 wc = *(const float4*)&CW[c * 3 + 8];
      s += xm.x * wa.x + x0.x * wa.y + xp.x * wa.z;
      s += xm.y * wa.w + x0.y * wb.x + xp.y * wb.y;
      s += xm.z * wb.z + x0.z * wb.w + xp.z * wc.x;
      s += xm.w * wc.y + x0.w * wc.z + xp.w * wc.w;
    }
    s += __shfl_xor(s, 8);
    s += __shfl_xor(s, 16);
    s += __shfl_xor(s, 32);
    if (p == 0) out[TS_OFF + grow] = 1.f / (1.f + expf(-(s + CB[0])));
  }

  // ---- GEMM1: (64x256)@(256x128), 8x4 per thread, BOTH operands from global
  //      with 1-k4-ahead register ping-pong prefetch. No LDS, no barriers.
  //      A: half-wave-broadcast row reads (L1/L2). B: coalesced W1 rows (L2). ----
  const int rt = tid >> 5, ct = tid & 31;   // 8 row-groups x 32 col-groups
  const int rb = rt * 8;
  const float* xb = X + (size_t)(row0 + rb) * C_;
  const float* wb1 = W1 + ct * 4;
  float4 acc[8];
  #pragma unroll
  for (int r = 0; r < 8; ++r) acc[r] = make_float4(0.f, 0.f, 0.f, 0.f);
  {
    float4 A0[8], A1[8], B0[4], B1[4];
    #pragma unroll
    for (int r = 0; r < 8; ++r) A0[r] = *(const float4*)&xb[r * C_];
    #pragma unroll
    for (int j = 0; j < 4; ++j) B0[j] = *(const float4*)&wb1[(size_t)j * H1_];

    #define G1STEP(Ac, Bc, An, Bn, kb, pf)                                        \
      {                                                                           \
        if (pf) {                                                                 \
          _Pragma("unroll")                                                       \
          for (int r = 0; r < 8; ++r) An[r] = *(const float4*)&xb[r * C_ + (kb) + 4]; \
          _Pragma("unroll")                                                       \
          for (int j = 0; j < 4; ++j) Bn[j] = *(const float4*)&wb1[(size_t)((kb) + 4 + j) * H1_]; \
        }                                                                         \
        _Pragma("unroll")                                                         \
        for (int r = 0; r < 8; ++r) {                                             \
          fma4(acc[r], Ac[r].x, Bc[0]); fma4(acc[r], Ac[r].y, Bc[1]);             \
          fma4(acc[r], Ac[r].z, Bc[2]); fma4(acc[r], Ac[r].w, Bc[3]);             \
        }                                                                         \
      }

    for (int k4 = 0; k4 < 64; k4 += 2) {
      G1STEP(A0, B0, A1, B1, k4 * 4, 1)
      G1STEP(A1, B1, A0, B0, k4 * 4 + 4, (k4 + 2 < 64))
    }
    #undef G1STEP
  }

  // ---- bias+relu -> H1S [64][132] (the only LDS use; one barrier) ----
  {
    float4 bb = ((const float4*)b1)[ct];
    #pragma unroll
    for (int r = 0; r < 8; ++r) {
      float4 h = acc[r];
      h.x = fmaxf(h.x + bb.x, 0.f); h.y = fmaxf(h.y + bb.y, 0.f);
      h.z = fmaxf(h.z + bb.z, 0.f); h.w = fmaxf(h.w + bb.w, 0.f);
      *(float4*)&sm[(rb + r) * H1S_P + ct * 4] = h;
    }
  }
  __syncthreads();

  // ---- GEMM2: (64x128)@(128x64), 4x4 per thread.
  //      A: H1S quarter-broadcast LDS reads. B: W2 from global, ping-pong. ----
  const int rt2 = tid >> 4, ct2 = tid & 15;
  // W3/b2/b3 loads issued here; latency hidden under GEMM2 compute
  float4 w30 = ((const float4*)W3)[ct2 * 4 + 0];
  float4 w31 = ((const float4*)W3)[ct2 * 4 + 1];
  float4 w32 = ((const float4*)W3)[ct2 * 4 + 2];
  float4 w33 = ((const float4*)W3)[ct2 * 4 + 3];
  float4 b2v = ((const float4*)b2)[ct2];
  float4 b3v = *(const float4*)&b3[0];
  const float* w2b = W2 + ct2 * 4;
  float4 acc2[4];
  #pragma unroll
  for (int j = 0; j < 4; ++j) acc2[j] = make_float4(0.f, 0.f, 0.f, 0.f);
  {
    float4 A0[4], A1[4], B0[4], B1[4];
    #pragma unroll
    for (int r = 0; r < 4; ++r) A0[r] = *(const float4*)&sm[(rt2 * 4 + r) * H1S_P];
    #pragma unroll
    for (int j = 0; j < 4; ++j) B0[j] = *(const float4*)&w2b[(size_t)j * H2_];

    #define G2STEP(Ac, Bc, An, Bn, kb, pf)                                        \
      {                                                                           \
        if (pf) {                                                                 \
          _Pragma("unroll")                                                       \
          for (int r = 0; r < 4; ++r) An[r] = *(const float4*)&sm[(rt2 * 4 + r) * H1S_P + (kb) + 4]; \
          _Pragma("unroll")                                                       \
          for (int j = 0; j < 4; ++j) Bn[j] = *(const float4*)&w2b[(size_t)((kb) + 4 + j) * H2_]; \
        }                                                                         \
        _Pragma("unroll")                                                         \
        for (int r = 0; r < 4; ++r) {                                             \
          fma4(acc2[r], Ac[r].x, Bc[0]); fma4(acc2[r], Ac[r].y, Bc[1]);           \
          fma4(acc2[r], Ac[r].z, Bc[2]); fma4(acc2[r], Ac[r].w, Bc[3]);           \
        }                                                                         \
      }

    for (int k4 = 0; k4 < 32; k4 += 2) {
      G2STEP(A0, B0, A1, B1, k4 * 4, 1)
      G2STEP(A1, B1, A0, B0, k4 * 4 + 4, (k4 + 2 < 32))
    }
    #undef G2STEP
  }

  // ---- ReLU+b2 (regs); GEMM3 partials; butterfly over 16 col-groups ----
  float4 L[4];
  {
    #pragma unroll
    for (int r = 0; r < 4; ++r) {
      float4 h = acc2[r];
      h.x = fmaxf(h.x + b2v.x, 0.f); h.y = fmaxf(h.y + b2v.y, 0.f);
      h.z = fmaxf(h.z + b2v.z, 0.f); h.w = fmaxf(h.w + b2v.w, 0.f);
      float4 t = make_float4(0.f, 0.f, 0.f, 0.f);
      fma4(t, h.x, w30); fma4(t, h.y, w31); fma4(t, h.z, w32); fma4(t, h.w, w33);
      L[r] = t;
    }
  }
  #pragma unroll
  for (int d = 1; d < 16; d <<= 1) {
    #pragma unroll
    for (int r = 0; r < 4; ++r) {
      L[r].x += __shfl_xor(L[r].x, d);
      L[r].y += __shfl_xor(L[r].y, d);
      L[r].z += __shfl_xor(L[r].z, d);
      L[r].w += __shfl_xor(L[r].w, d);
    }
  }

  // ---- softmax + dom/conf: lane ct2 (0..3) handles row rt2*4 + ct2 ----
  if (ct2 < 4) {
    float4 Lv = L[ct2];
    const int grow = row0 + rt2 * 4 + ct2;
    Lv.x += b3v.x; Lv.y += b3v.y; Lv.z += b3v.z; Lv.w += b3v.w;
    float mx = fmaxf(fmaxf(Lv.x, Lv.y), fmaxf(Lv.z, Lv.w));
    float e0 = expf(Lv.x - mx), e1 = expf(Lv.y - mx), e2 = expf(Lv.z - mx), e3 = expf(Lv.w - mx);
    float inv = 1.f / ((e0 + e1) + (e2 + e3));
    float p0 = e0 * inv, p1 = e1 * inv, p2 = e2 * inv, p3 = e3 * inv;
    *(float4*)&out[PROBS_OFF + (size_t)grow * 4] = make_float4(p0, p1, p2, p3);
    int dom = 0; float pm = p0;
    if (p1 > pm) { pm = p1; dom = 1; }
    if (p2 > pm) { pm = p2; dom = 2; }
    if (p3 > pm) { pm = p3; dom = 3; }
    out[MI_OFF + grow] = (float)dom;   // park dom for kernel 2
    out[MC_OFF + grow] = pm;           // park conf for kernel 2
  }
}

// ---- kernel 2: per-batch-row segmentation + segment means ----
__global__ __launch_bounds__(1024, 1) void seg_kernel(
    const float* __restrict__ inten, float* __restrict__ out)
{
  __shared__ float scnt[T_], ssi[T_], ssc[T_];
  __shared__ int wtot[16], wexcl[16];
  const int tid = threadIdx.x;
  const int lane = tid & 63, wid = tid >> 6;
  const size_t base = (size_t)blockIdx.x * T_;
  const float* tsS = out + TS_OFF;
  float* segO = out + SEG_OFF;
  float* miO  = out + MI_OFF;
  float* mcO  = out + MC_OFF;
  const int t4 = tid * 4;

  float4 dv = *(const float4*)&miO[base + t4];        // dom (as float)
  float4 tv = *(const float4*)&tsS[base + t4];        // transition scores
  float4 iv = *(const float4*)&inten[base + t4];      // intensity
  float4 cv = *(const float4*)&mcO[base + t4];        // confidence
  float pd = (tid == 0) ? 0.f : miO[base + t4 - 1];

  for (int i = tid; i < T_; i += 1024) { scnt[i] = 0.f; ssi[i] = 0.f; ssc[i] = 0.f; }

  int c0 = (t4 == 0) ? 0 : (((dv.x != pd)   || (tv.x > 0.7f)) ? 1 : 0);
  int c1 = ((dv.y != dv.x) || (tv.y > 0.7f)) ? 1 : 0;
  int c2 = ((dv.z != dv.y) || (tv.z > 0.7f)) ? 1 : 0;
  int c3 = ((dv.w != dv.z) || (tv.w > 0.7f)) ? 1 : 0;
  int l0 = c0, l1 = c0 + c1, l2 = l1 + c2, l3 = l2 + c3;
  const int tsum = l3;

  // wave-inclusive scan of per-thread sums
  int v = tsum;
  #pragma unroll
  for (int d = 1; d < 64; d <<= 1) {
    int o = __shfl_up(v, (unsigned)d);
    if (lane >= d) v += o;
  }
  if (lane == 63) wtot[wid] = v;
  __syncthreads();
  if (tid < 16) {
    int x = wtot[tid];
    int xx = x;
    #pragma unroll
    for (int d = 1; d < 16; d <<= 1) {
      int o = __shfl_up(xx, (unsigned)d);
      if (tid >= d) xx += o;
    }
    wexcl[tid] = xx - x;   // exclusive wave offset
  }
  __syncthreads();
  const int texcl = wexcl[wid] + (v - tsum);
  const int s0 = texcl + l0, s1 = texcl + l1, s2 = texcl + l2, s3 = texcl + l3;

  // merged LDS atomics for segment sums
  {
    int cur = s0; float aI = iv.x, aC = cv.x, aN = 1.f;
    if (s1 == cur) { aI += iv.y; aC += cv.y; aN += 1.f; }
    else { atomicAdd(&ssi[cur], aI); atomicAdd(&ssc[cur], aC); atomicAdd(&scnt[cur], aN);
           cur = s1; aI = iv.y; aC = cv.y; aN = 1.f; }
    if (s2 == cur) { aI += iv.z; aC += cv.z; aN += 1.f; }
    else { atomicAdd(&ssi[cur], aI); atomicAdd(&ssc[cur], aC); atomicAdd(&scnt[cur], aN);
           cur = s2; aI = iv.z; aC = cv.z; aN = 1.f; }
    if (s3 == cur) { aI += iv.w; aC += cv.w; aN += 1.f; }
    else { atomicAdd(&ssi[cur], aI); atomicAdd(&ssc[cur], aC); atomicAdd(&scnt[cur], aN);
           cur = s3; aI = iv.w; aC = cv.w; aN = 1.f; }
    atomicAdd(&ssi[cur], aI); atomicAdd(&ssc[cur], aC); atomicAdd(&scnt[cur], aN);
  }
  __syncthreads();

  float n0 = scnt[s0], n1 = scnt[s1], n2 = scnt[s2], n3 = scnt[s3];
  float4 m4, q4, g4;
  m4.x = ssi[s0] / n0; m4.y = ssi[s1] / n1; m4.z = ssi[s2] / n2; m4.w = ssi[s3] / n3;
  q4.x = ssc[s0] / n0; q4.y = ssc[s1] / n1; q4.z = ssc[s2] / n2; q4.w = ssc[s3] / n3;
  g4.x = (float)s0; g4.y = (float)s1; g4.z = (float)s2; g4.w = (float)s3;
  *(float4*)&segO[base + t4] = g4;
  *(float4*)&miO[base + t4]  = m4;
  *(float4*)&mcO[base + t4]  = q4;
}

extern "C" void kernel_launch(void* const* d_in, const int* in_sizes, int n_in,
                              void* d_out, int out_size, void* d_ws, size_t ws_size,
                              hipStream_t stream) {
  (void)in_sizes; (void)n_in; (void)out_size; (void)d_ws; (void)ws_size;
  const float* X   = (const float*)d_in[0];
  const float* INT = (const float*)d_in[1];
  const float* W1  = (const float*)d_in[2];
  const float* B1  = (const float*)d_in[3];
  const float* W2  = (const float*)d_in[4];
  const float* B2  = (const float*)d_in[5];
  const float* W3  = (const float*)d_in[6];
  const float* B3  = (const float*)d_in[7];
  const float* CW  = (const float*)d_in[8];
  const float* CB  = (const float*)d_in[9];
  float* out = (float*)d_out;

  hipLaunchKernelGGL(mlp_conv_kernel, dim3(R_ / TB), dim3(256), 0, stream,
                     X, W1, B1, W2, B2, W3, B3, CW, CB, out);
  hipLaunchKernelGGL(seg_kernel, dim3(B_), dim3(1024), 0, stream, INT, out);
}

// Round 11
// 508.187 us; speedup vs baseline: 1.0125x; 1.0125x over previous
//
#include <hip/hip_runtime.h>

#define B_ 32
#define T_ 4096
#define C_ 256
#define R_ (B_*T_)
#define H1_ 128
#define H2_ 64

#define TB 64   // timestep rows per block in kernel 1

// output layout (floats), concatenated in reference return order
#define PROBS_OFF 0
#define TS_OFF  (R_*4)
#define SEG_OFF (TS_OFF + R_)
#define MI_OFF  (SEG_OFF + R_)
#define MC_OFF  (MI_OFF + R_)

// LDS: only H1 [64][132] = 8448 floats = 33.8 KB -> 3 blocks/CU.
#define H1S_P   132
#define SMEMF   (64 * H1S_P)

__device__ __forceinline__ void fma4(float4& a, float s, const float4& b) {
  a.x = fmaf(s, b.x, a.x); a.y = fmaf(s, b.y, a.y);
  a.z = fmaf(s, b.z, a.z); a.w = fmaf(s, b.w, a.w);
}

__global__ __launch_bounds__(256, 3) void mlp_conv_kernel(
    const float* __restrict__ X, const float* __restrict__ W1, const float* __restrict__ b1,
    const float* __restrict__ W2, const float* __restrict__ b2,
    const float* __restrict__ W3, const float* __restrict__ b3,
    const float* __restrict__ CW, const float* __restrict__ CB,
    float* __restrict__ out)
{
  __shared__ float sm[SMEMF];
  const int tid  = threadIdx.x;
  const int l    = tid & 63;
  const int w    = tid >> 6;
  const int row0 = blockIdx.x * TB;

  // ---- conv1d (C->1, k=3, SAME) + sigmoid, straight from global (L1-backed).
  //      Identical per-row arithmetic to R8 (bit-identical ts). ----
  #pragma unroll
  for (int half = 0; half < 2; ++half) {
    const int rowi = half * 32 + w * 8 + (l & 7);
    const int p = l >> 3;                        // 0..7
    const int grow = row0 + rowi;
    const int tb = grow & (T_ - 1);              // t within its batch row
    const float* x0p = X + (size_t)grow * C_;
    float s = 0.f;
    #pragma unroll
    for (int cc = 0; cc < 8; ++cc) {
      const int c = p * 32 + cc * 4;
      float4 x0 = *(const float4*)&x0p[c];
      float4 xm, xp;
      if (tb == 0)        xm = make_float4(0.f, 0.f, 0.f, 0.f);
      else                xm = *(const float4*)&x0p[c - C_];
      if (tb == T_ - 1)   xp = make_float4(0.f, 0.f, 0.f, 0.f);
      else                xp = *(const float4*)&x0p[c + C_];
      // conv_w flat layout: [c][k], k=0->x[t-1], 1->x[t], 2->x[t+1]
      float4 wa = *(const float4*)&CW[c * 3 + 0];
      float4 wb = *(const float4*)&CW[c * 3 + 4];
      float4 wc = *(const float4*)&CW[c * 3 + 8];
      s += xm.x * wa.x + x0.x * wa.y + xp.x * wa.z;
      s += xm.y * wa.w + x0.y * wb.x + xp.y * wb.y;
      s += xm.z * wb.z + x0.z * wb.w + xp.z * wc.x;
      s += xm.w * wc.y + x0.w * wc.z + xp.w * wc.w;
    }
    s += __shfl_xor(s, 8);
    s += __shfl_xor(s, 16);
    s += __shfl_xor(s, 32);
    if (p == 0) out[TS_OFF + grow] = 1.f / (1.f + expf(-(s + CB[0])));
  }

  // ---- GEMM1: (64x256)@(256x128), 8x4 per thread, BOTH operands from global
  //      with 1-k4-ahead register ping-pong prefetch. No LDS, no barriers.
  //      A: half-wave-broadcast row reads (L1/L2). B: coalesced W1 rows (L2). ----
  const int rt = tid >> 5, ct = tid & 31;   // 8 row-groups x 32 col-groups
  const int rb = rt * 8;
  const float* xb = X + (size_t)(row0 + rb) * C_;
  const float* wb1 = W1 + ct * 4;
  float4 acc[8];
  #pragma unroll
  for (int r = 0; r < 8; ++r) acc[r] = make_float4(0.f, 0.f, 0.f, 0.f);
  {
    float4 A0[8], A1[8], B0[4], B1[4];
    #pragma unroll
    for (int r = 0; r < 8; ++r) A0[r] = *(const float4*)&xb[r * C_];
    #pragma unroll
    for (int j = 0; j < 4; ++j) B0[j] = *(const float4*)&wb1[(size_t)j * H1_];

    #define G1STEP(Ac, Bc, An, Bn, kb, pf)                                        \
      {                                                                           \
        if (pf) {                                                                 \
          _Pragma("unroll")                                                       \
          for (int r = 0; r < 8; ++r) An[r] = *(const float4*)&xb[r * C_ + (kb) + 4]; \
          _Pragma("unroll")                                                       \
          for (int j = 0; j < 4; ++j) Bn[j] = *(const float4*)&wb1[(size_t)((kb) + 4 + j) * H1_]; \
        }                                                                         \
        _Pragma("unroll")                                                         \
        for (int r = 0; r < 8; ++r) {                                             \
          fma4(acc[r], Ac[r].x, Bc[0]); fma4(acc[r], Ac[r].y, Bc[1]);             \
          fma4(acc[r], Ac[r].z, Bc[2]); fma4(acc[r], Ac[r].w, Bc[3]);             \
        }                                                                         \
      }

    for (int k4 = 0; k4 < 64; k4 += 2) {
      G1STEP(A0, B0, A1, B1, k4 * 4, 1)
      G1STEP(A1, B1, A0, B0, k4 * 4 + 4, (k4 + 2 < 64))
    }
    #undef G1STEP
  }

  // ---- bias+relu -> H1S [64][132] (the only LDS use; one barrier) ----
  {
    float4 bb = ((const float4*)b1)[ct];
    #pragma unroll
    for (int r = 0; r < 8; ++r) {
      float4 h = acc[r];
      h.x = fmaxf(h.x + bb.x, 0.f); h.y = fmaxf(h.y + bb.y, 0.f);
      h.z = fmaxf(h.z + bb.z, 0.f); h.w = fmaxf(h.w + bb.w, 0.f);
      *(float4*)&sm[(rb + r) * H1S_P + ct * 4] = h;
    }
  }
  __syncthreads();

  // ---- GEMM2: (64x128)@(128x64), 4x4 per thread.
  //      A: H1S quarter-broadcast LDS reads. B: W2 from global, ping-pong. ----
  const int rt2 = tid >> 4, ct2 = tid & 15;
  // W3/b2/b3 loads issued here; latency hidden under GEMM2 compute
  float4 w30 = ((const float4*)W3)[ct2 * 4 + 0];
  float4 w31 = ((const float4*)W3)[ct2 * 4 + 1];
  float4 w32 = ((const float4*)W3)[ct2 * 4 + 2];
  float4 w33 = ((const float4*)W3)[ct2 * 4 + 3];
  float4 b2v = ((const float4*)b2)[ct2];
  float4 b3v = *(const float4*)&b3[0];
  const float* w2b = W2 + ct2 * 4;
  float4 acc2[4];
  #pragma unroll
  for (int j = 0; j < 4; ++j) acc2[j] = make_float4(0.f, 0.f, 0.f, 0.f);
  {
    float4 A0[4], A1[4], B0[4], B1[4];
    #pragma unroll
    for (int r = 0; r < 4; ++r) A0[r] = *(const float4*)&sm[(rt2 * 4 + r) * H1S_P];
    #pragma unroll
    for (int j = 0; j < 4; ++j) B0[j] = *(const float4*)&w2b[(size_t)j * H2_];

    #define G2STEP(Ac, Bc, An, Bn, kb, pf)                                        \
      {                                                                           \
        if (pf) {                                                                 \
          _Pragma("unroll")                                                       \
          for (int r = 0; r < 4; ++r) An[r] = *(const float4*)&sm[(rt2 * 4 + r) * H1S_P + (kb) + 4]; \
          _Pragma("unroll")                                                       \
          for (int j = 0; j < 4; ++j) Bn[j] = *(const float4*)&w2b[(size_t)((kb) + 4 + j) * H2_]; \
        }                                                                         \
        _Pragma("unroll")                                                         \
        for (int r = 0; r < 4; ++r) {                                             \
          fma4(acc2[r], Ac[r].x, Bc[0]); fma4(acc2[r], Ac[r].y, Bc[1]);           \
          fma4(acc2[r], Ac[r].z, Bc[2]); fma4(acc2[r], Ac[r].w, Bc[3]);           \
        }                                                                         \
      }

    for (int k4 = 0; k4 < 32; k4 += 2) {
      G2STEP(A0, B0, A1, B1, k4 * 4, 1)
      G2STEP(A1, B1, A0, B0, k4 * 4 + 4, (k4 + 2 < 32))
    }
    #undef G2STEP
  }

  // ---- ReLU+b2 (regs); GEMM3 partials; butterfly over 16 col-groups ----
  float4 L[4];
  {
    #pragma unroll
    for (int r = 0; r < 4; ++r) {
      float4 h = acc2[r];
      h.x = fmaxf(h.x + b2v.x, 0.f); h.y = fmaxf(h.y + b2v.y, 0.f);
      h.z = fmaxf(h.z + b2v.z, 0.f); h.w = fmaxf(h.w + b2v.w, 0.f);
      float4 t = make_float4(0.f, 0.f, 0.f, 0.f);
      fma4(t, h.x, w30); fma4(t, h.y, w31); fma4(t, h.z, w32); fma4(t, h.w, w33);
      L[r] = t;
    }
  }
  #pragma unroll
  for (int d = 1; d < 16; d <<= 1) {
    #pragma unroll
    for (int r = 0; r < 4; ++r) {
      L[r].x += __shfl_xor(L[r].x, d);
      L[r].y += __shfl_xor(L[r].y, d);
      L[r].z += __shfl_xor(L[r].z, d);
      L[r].w += __shfl_xor(L[r].w, d);
    }
  }

  // ---- softmax + dom/conf: lane ct2 (0..3) handles row rt2*4 + ct2 ----
  if (ct2 < 4) {
    float4 Lv = L[ct2];
    const int grow = row0 + rt2 * 4 + ct2;
    Lv.x += b3v.x; Lv.y += b3v.y; Lv.z += b3v.z; Lv.w += b3v.w;
    float mx = fmaxf(fmaxf(Lv.x, Lv.y), fmaxf(Lv.z, Lv.w));
    float e0 = expf(Lv.x - mx), e1 = expf(Lv.y - mx), e2 = expf(Lv.z - mx), e3 = expf(Lv.w - mx);
    float inv = 1.f / ((e0 + e1) + (e2 + e3));
    float p0 = e0 * inv, p1 = e1 * inv, p2 = e2 * inv, p3 = e3 * inv;
    *(float4*)&out[PROBS_OFF + (size_t)grow * 4] = make_float4(p0, p1, p2, p3);
    int dom = 0; float pm = p0;
    if (p1 > pm) { pm = p1; dom = 1; }
    if (p2 > pm) { pm = p2; dom = 2; }
    if (p3 > pm) { pm = p3; dom = 3; }
    out[MI_OFF + grow] = (float)dom;   // park dom for kernel 2
    out[MC_OFF + grow] = pm;           // park conf for kernel 2
  }
}

// ---- kernel 2: per-batch-row segmentation + segment means ----
__global__ __launch_bounds__(1024, 1) void seg_kernel(
    const float* __restrict__ inten, float* __restrict__ out)
{
  __shared__ float scnt[T_], ssi[T_], ssc[T_];
  __shared__ int wtot[16], wexcl[16];
  const int tid = threadIdx.x;
  const int lane = tid & 63, wid = tid >> 6;
  const size_t base = (size_t)blockIdx.x * T_;
  const float* tsS = out + TS_OFF;
  float* segO = out + SEG_OFF;
  float* miO  = out + MI_OFF;
  float* mcO  = out + MC_OFF;
  const int t4 = tid * 4;

  float4 dv = *(const float4*)&miO[base + t4];        // dom (as float)
  float4 tv = *(const float4*)&tsS[base + t4];        // transition scores
  float4 iv = *(const float4*)&inten[base + t4];      // intensity
  float4 cv = *(const float4*)&mcO[base + t4];        // confidence
  float pd = (tid == 0) ? 0.f : miO[base + t4 - 1];

  for (int i = tid; i < T_; i += 1024) { scnt[i] = 0.f; ssi[i] = 0.f; ssc[i] = 0.f; }

  int c0 = (t4 == 0) ? 0 : (((dv.x != pd)   || (tv.x > 0.7f)) ? 1 : 0);
  int c1 = ((dv.y != dv.x) || (tv.y > 0.7f)) ? 1 : 0;
  int c2 = ((dv.z != dv.y) || (tv.z > 0.7f)) ? 1 : 0;
  int c3 = ((dv.w != dv.z) || (tv.w > 0.7f)) ? 1 : 0;
  int l0 = c0, l1 = c0 + c1, l2 = l1 + c2, l3 = l2 + c3;
  const int tsum = l3;

  // wave-inclusive scan of per-thread sums
  int v = tsum;
  #pragma unroll
  for (int d = 1; d < 64; d <<= 1) {
    int o = __shfl_up(v, (unsigned)d);
    if (lane >= d) v += o;
  }
  if (lane == 63) wtot[wid] = v;
  __syncthreads();
  if (tid < 16) {
    int x = wtot[tid];
    int xx = x;
    #pragma unroll
    for (int d = 1; d < 16; d <<= 1) {
      int o = __shfl_up(xx, (unsigned)d);
      if (tid >= d) xx += o;
    }
    wexcl[tid] = xx - x;   // exclusive wave offset
  }
  __syncthreads();
  const int texcl = wexcl[wid] + (v - tsum);
  const int s0 = texcl + l0, s1 = texcl + l1, s2 = texcl + l2, s3 = texcl + l3;

  // merged LDS atomics for segment sums
  {
    int cur = s0; float aI = iv.x, aC = cv.x, aN = 1.f;
    if (s1 == cur) { aI += iv.y; aC += cv.y; aN += 1.f; }
    else { atomicAdd(&ssi[cur], aI); atomicAdd(&ssc[cur], aC); atomicAdd(&scnt[cur], aN);
           cur = s1; aI = iv.y; aC = cv.y; aN = 1.f; }
    if (s2 == cur) { aI += iv.z; aC += cv.z; aN += 1.f; }
    else { atomicAdd(&ssi[cur], aI); atomicAdd(&ssc[cur], aC); atomicAdd(&scnt[cur], aN);
           cur = s2; aI = iv.z; aC = cv.z; aN = 1.f; }
    if (s3 == cur) { aI += iv.w; aC += cv.w; aN += 1.f; }
    else { atomicAdd(&ssi[cur], aI); atomicAdd(&ssc[cur], aC); atomicAdd(&scnt[cur], aN);
           cur = s3; aI = iv.w; aC = cv.w; aN = 1.f; }
    atomicAdd(&ssi[cur], aI); atomicAdd(&ssc[cur], aC); atomicAdd(&scnt[cur], aN);
  }
  __syncthreads();

  float n0 = scnt[s0], n1 = scnt[s1], n2 = scnt[s2], n3 = scnt[s3];
  float4 m4, q4, g4;
  m4.x = ssi[s0] / n0; m4.y = ssi[s1] / n1; m4.z = ssi[s2] / n2; m4.w = ssi[s3] / n3;
  q4.x = ssc[s0] / n0; q4.y = ssc[s1] / n1; q4.z = ssc[s2] / n2; q4.w = ssc[s3] / n3;
  g4.x = (float)s0; g4.y = (float)s1; g4.z = (float)s2; g4.w = (float)s3;
  *(float4*)&segO[base + t4] = g4;
  *(float4*)&miO[base + t4]  = m4;
  *(float4*)&mcO[base + t4]  = q4;
}

extern "C" void kernel_launch(void* const* d_in, const int* in_sizes, int n_in,
                              void* d_out, int out_size, void* d_ws, size_t ws_size,
                              hipStream_t stream) {
  (void)in_sizes; (void)n_in; (void)out_size; (void)d_ws; (void)ws_size;
  const float* X   = (const float*)d_in[0];
  const float* INT = (const float*)d_in[1];
  const float* W1  = (const float*)d_in[2];
  const float* B1  = (const float*)d_in[3];
  const float* W2  = (const float*)d_in[4];
  const float* B2  = (const float*)d_in[5];
  const float* W3  = (const float*)d_in[6];
  const float* B3  = (const float*)d_in[7];
  const float* CW  = (const float*)d_in[8];
  const float* CB  = (const float*)d_in[9];
  float* out = (float*)d_out;

  hipLaunchKernelGGL(mlp_conv_kernel, dim3(R_ / TB), dim3(256), 0, stream,
                     X, W1, B1, W2, B2, W3, B3, CW, CB, out);
  hipLaunchKernelGGL(seg_kernel, dim3(B_), dim3(1024), 0, stream, INT, out);
}

// Round 12
// 310.712 us; speedup vs baseline: 1.6560x; 1.6356x over previous
//
#include <hip/hip_runtime.h>

#define B_ 32
#define T_ 4096
#define C_ 256
#define R_ (B_*T_)
#define H1_ 128
#define H2_ 64

#define TB 64   // timestep rows per block in kernel 1

// output layout (floats), concatenated in reference return order
#define PROBS_OFF 0
#define TS_OFF  (R_*4)
#define SEG_OFF (TS_OFF + R_)
#define MI_OFF  (SEG_OFF + R_)
#define MC_OFF  (MI_OFF + R_)

// LDS float layout, 12544 floats = 50.2 KB -> 3 blocks/CU:
//   XS  [64][132] at 0     (one 128-ch K-half of the X tile; -> H1S later)
//   W1S [16][128] at 8448  (2048 f; -> W2S [64][64] 4096 f later)
#define XS_OFF  0
#define XS_P    132
#define H1S_OFF 0
#define H1S_P   132
#define W1S_OFF 8448
#define W2S_OFF 8448
#define SMEMF   12544

__device__ __forceinline__ void fma4(float4& a, float s, const float4& b) {
  a.x = fmaf(s, b.x, a.x); a.y = fmaf(s, b.y, a.y);
  a.z = fmaf(s, b.z, a.z); a.w = fmaf(s, b.w, a.w);
}

// conv partial over one 16-channel slice of one K-half, one row-half
#define CONVPART(hh, khalf, svar)                                                  \
  {                                                                                \
    const int rowi = (hh) * 32 + w * 8 + (l & 7);                                  \
    const int p_ = l >> 3;                                                         \
    const int grow = row0 + rowi;                                                  \
    const int tb = grow & (T_ - 1);                                                \
    _Pragma("unroll")                                                              \
    for (int cc = 0; cc < 4; ++cc) {                                               \
      const int cl = p_ * 16 + cc * 4;                                             \
      const int cabs = (khalf) * 128 + cl;                                         \
      float4 x0 = *(const float4*)&sm[XS_OFF + rowi * XS_P + cl];                  \
      float4 xm, xp;                                                               \
      if (tb == 0)            xm = make_float4(0.f, 0.f, 0.f, 0.f);                \
      else if (rowi >= 1)     xm = *(const float4*)&sm[XS_OFF + (rowi - 1) * XS_P + cl]; \
      else                    xm = *(const float4*)&X[(size_t)(grow - 1) * C_ + cabs];   \
      if (tb == T_ - 1)       xp = make_float4(0.f, 0.f, 0.f, 0.f);                \
      else if (rowi + 1 < TB) xp = *(const float4*)&sm[XS_OFF + (rowi + 1) * XS_P + cl]; \
      else                    xp = *(const float4*)&X[(size_t)(grow + 1) * C_ + cabs];   \
      float4 wa = *(const float4*)&CW[cabs * 3 + 0];                               \
      float4 wb = *(const float4*)&CW[cabs * 3 + 4];                               \
      float4 wc = *(const float4*)&CW[cabs * 3 + 8];                               \
      svar += xm.x * wa.x + x0.x * wa.y + xp.x * wa.z;                             \
      svar += xm.y * wa.w + x0.y * wb.x + xp.y * wb.y;                             \
      svar += xm.z * wb.z + x0.z * wb.w + xp.z * wc.x;                             \
      svar += xm.w * wc.y + x0.w * wc.z + xp.w * wc.w;                             \
    }                                                                              \
  }

__global__ __launch_bounds__(256, 3) void mlp_conv_kernel(
    const float* __restrict__ X, const float* __restrict__ W1, const float* __restrict__ b1,
    const float* __restrict__ W2, const float* __restrict__ b2,
    const float* __restrict__ W3, const float* __restrict__ b3,
    const float* __restrict__ CW, const float* __restrict__ CB,
    float* __restrict__ out)
{
  __shared__ float sm[SMEMF];
  const int tid  = threadIdx.x;
  const int l    = tid & 63;
  const int w    = tid >> 6;
  const int row0 = blockIdx.x * TB;

  // ---- W1 chunk 0 (16 k-rows) prefetch into regs ----
  float4 st0 = ((const float4*)W1)[tid];
  float4 st1 = ((const float4*)W1)[tid + 256];
  float4 w2a = make_float4(0.f, 0.f, 0.f, 0.f), w2b = w2a;

  const int rt = tid >> 5, ct = tid & 31;   // 8 row-groups x 32 col-groups
  const int rb = rt * 8;
  float sA = 0.f, sB = 0.f;                 // conv partials (rows rowA/rowB)
  float4 acc[8];
  #pragma unroll
  for (int r = 0; r < 8; ++r) acc[r] = make_float4(0.f, 0.f, 0.f, 0.f);

  #pragma unroll
  for (int khalf = 0; khalf < 2; ++khalf) {
    // ---- stage X K-half tile (64 rows x 128 ch) into XS ----
    // (khalf=1 restage is safe: previous phase ended with __syncthreads)
    #pragma unroll
    for (int i2 = 0; i2 < 8; ++i2) {
      int g = tid + 256 * i2;          // 2048 f4: 64 rows x 32 f4
      int r = g >> 5, m = g & 31;
      float4 v = *(const float4*)&X[(size_t)(row0 + r) * C_ + khalf * 128 + m * 4];
      *(float4*)&sm[XS_OFF + r * XS_P + m * 4] = v;
    }
    __syncthreads();

    // ---- conv partials for this K-half (both row halves) ----
    CONVPART(0, khalf, sA)
    CONVPART(1, khalf, sB)
    if (khalf == 1) {   // finalize conv: reduce over 8 partials, sigmoid, store
      const int p_ = l >> 3;
      float s = sA;
      s += __shfl_xor(s, 8); s += __shfl_xor(s, 16); s += __shfl_xor(s, 32);
      if (p_ == 0) out[TS_OFF + row0 + w * 8 + (l & 7)] =
        1.f / (1.f + expf(-(s + CB[0])));
      s = sB;
      s += __shfl_xor(s, 8); s += __shfl_xor(s, 16); s += __shfl_xor(s, 32);
      if (p_ == 0) out[TS_OFF + row0 + 32 + w * 8 + (l & 7)] =
        1.f / (1.f + expf(-(s + CB[0])));
    }

    // ---- GEMM1 for this K-half: 8 chunks of 16 k-rows ----
    for (int kcl = 0; kcl < 8; ++kcl) {
      *(float4*)&sm[W1S_OFF + tid * 4]         = st0;
      *(float4*)&sm[W1S_OFF + (tid + 256) * 4] = st1;
      __syncthreads();
      const int kcg = khalf * 8 + kcl;
      if (kcg + 1 < 16) {   // prefetch next W1 chunk (hidden under compute)
        const float* wp = W1 + (size_t)(kcg + 1) * 2048;
        st0 = ((const float4*)wp)[tid];
        st1 = ((const float4*)wp)[tid + 256];
      } else {              // prefetch W2 chunk 0 (k-rows 0..63)
        st0 = ((const float4*)W2)[tid];
        st1 = ((const float4*)W2)[tid + 256];
        w2a = ((const float4*)W2)[tid + 512];
        w2b = ((const float4*)W2)[tid + 768];
      }
      #pragma unroll
      for (int k4 = 0; k4 < 4; ++k4) {
        const int colb = kcl * 16 + k4 * 4;
        float4 a0 = *(const float4*)&sm[XS_OFF + (rb + 0) * XS_P + colb];
        float4 a1 = *(const float4*)&sm[XS_OFF + (rb + 1) * XS_P + colb];
        float4 a2 = *(const float4*)&sm[XS_OFF + (rb + 2) * XS_P + colb];
        float4 a3 = *(const float4*)&sm[XS_OFF + (rb + 3) * XS_P + colb];
        float4 a4 = *(const float4*)&sm[XS_OFF + (rb + 4) * XS_P + colb];
        float4 a5 = *(const float4*)&sm[XS_OFF + (rb + 5) * XS_P + colb];
        float4 a6 = *(const float4*)&sm[XS_OFF + (rb + 6) * XS_P + colb];
        float4 a7 = *(const float4*)&sm[XS_OFF + (rb + 7) * XS_P + colb];
        float4 q0 = *(const float4*)&sm[W1S_OFF + (k4 * 4 + 0) * H1_ + ct * 4];
        float4 q1 = *(const float4*)&sm[W1S_OFF + (k4 * 4 + 1) * H1_ + ct * 4];
        float4 q2 = *(const float4*)&sm[W1S_OFF + (k4 * 4 + 2) * H1_ + ct * 4];
        float4 q3 = *(const float4*)&sm[W1S_OFF + (k4 * 4 + 3) * H1_ + ct * 4];
        fma4(acc[0], a0.x, q0); fma4(acc[0], a0.y, q1); fma4(acc[0], a0.z, q2); fma4(acc[0], a0.w, q3);
        fma4(acc[1], a1.x, q0); fma4(acc[1], a1.y, q1); fma4(acc[1], a1.z, q2); fma4(acc[1], a1.w, q3);
        fma4(acc[2], a2.x, q0); fma4(acc[2], a2.y, q1); fma4(acc[2], a2.z, q2); fma4(acc[2], a2.w, q3);
        fma4(acc[3], a3.x, q0); fma4(acc[3], a3.y, q1); fma4(acc[3], a3.z, q2); fma4(acc[3], a3.w, q3);
        fma4(acc[4], a4.x, q0); fma4(acc[4], a4.y, q1); fma4(acc[4], a4.z, q2); fma4(acc[4], a4.w, q3);
        fma4(acc[5], a5.x, q0); fma4(acc[5], a5.y, q1); fma4(acc[5], a5.z, q2); fma4(acc[5], a5.w, q3);
        fma4(acc[6], a6.x, q0); fma4(acc[6], a6.y, q1); fma4(acc[6], a6.z, q2); fma4(acc[6], a6.w, q3);
        fma4(acc[7], a7.x, q0); fma4(acc[7], a7.y, q1); fma4(acc[7], a7.z, q2); fma4(acc[7], a7.w, q3);
      }
      __syncthreads();   // all reads of this chunk (XS + W1S) done before next write
    }
  }

  // ---- epilogue regs (W3/b2/b3; latency hidden under H1 writes) ----
  const int rt2 = tid >> 4, ct2 = tid & 15;
  float4 w30 = ((const float4*)W3)[ct2 * 4 + 0];
  float4 w31 = ((const float4*)W3)[ct2 * 4 + 1];
  float4 w32 = ((const float4*)W3)[ct2 * 4 + 2];
  float4 w33 = ((const float4*)W3)[ct2 * 4 + 3];
  float4 b2v = ((const float4*)b2)[ct2];
  float4 b3v = *(const float4*)&b3[0];

  // ---- bias+relu -> H1S [64][132] (overlays XS, dead) ----
  {
    float4 bb = ((const float4*)b1)[ct];
    #pragma unroll
    for (int r = 0; r < 8; ++r) {
      float4 h = acc[r];
      h.x = fmaxf(h.x + bb.x, 0.f); h.y = fmaxf(h.y + bb.y, 0.f);
      h.z = fmaxf(h.z + bb.z, 0.f); h.w = fmaxf(h.w + bb.w, 0.f);
      *(float4*)&sm[H1S_OFF + (rb + r) * H1S_P + ct * 4] = h;
    }
  }
  // W2 chunk 0 -> W2S [64][64] (overlays W1S, dead)
  *(float4*)&sm[W2S_OFF + tid * 4]         = st0;
  *(float4*)&sm[W2S_OFF + (tid + 256) * 4] = st1;
  *(float4*)&sm[W2S_OFF + (tid + 512) * 4] = w2a;
  *(float4*)&sm[W2S_OFF + (tid + 768) * 4] = w2b;
  __syncthreads();

  // prefetch W2 chunk 1 (k-rows 64..127) — consumed after next barrier
  st0 = ((const float4*)W2)[tid + 1024];
  st1 = ((const float4*)W2)[tid + 1280];
  w2a = ((const float4*)W2)[tid + 1536];
  w2b = ((const float4*)W2)[tid + 1792];

  // ---- GEMM2: (64x128)@(128x64), 4x4 per thread; W2 in two 64-k chunks ----
  float4 acc2[4];
  #pragma unroll
  for (int j = 0; j < 4; ++j) acc2[j] = make_float4(0.f, 0.f, 0.f, 0.f);
  #pragma unroll 4
  for (int k4 = 0; k4 < 16; ++k4) {          // k 0..63
    float4 a0 = *(const float4*)&sm[H1S_OFF + (rt2 * 4 + 0) * H1S_P + k4 * 4];
    float4 a1 = *(const float4*)&sm[H1S_OFF + (rt2 * 4 + 1) * H1S_P + k4 * 4];
    float4 a2 = *(const float4*)&sm[H1S_OFF + (rt2 * 4 + 2) * H1S_P + k4 * 4];
    float4 a3 = *(const float4*)&sm[H1S_OFF + (rt2 * 4 + 3) * H1S_P + k4 * 4];
    float4 q0 = *(const float4*)&sm[W2S_OFF + (k4 * 4 + 0) * H2_ + ct2 * 4];
    float4 q1 = *(const float4*)&sm[W2S_OFF + (k4 * 4 + 1) * H2_ + ct2 * 4];
    float4 q2 = *(const float4*)&sm[W2S_OFF + (k4 * 4 + 2) * H2_ + ct2 * 4];
    float4 q3 = *(const float4*)&sm[W2S_OFF + (k4 * 4 + 3) * H2_ + ct2 * 4];
    fma4(acc2[0], a0.x, q0); fma4(acc2[0], a0.y, q1); fma4(acc2[0], a0.z, q2); fma4(acc2[0], a0.w, q3);
    fma4(acc2[1], a1.x, q0); fma4(acc2[1], a1.y, q1); fma4(acc2[1], a1.z, q2); fma4(acc2[1], a1.w, q3);
    fma4(acc2[2], a2.x, q0); fma4(acc2[2], a2.y, q1); fma4(acc2[2], a2.z, q2); fma4(acc2[2], a2.w, q3);
    fma4(acc2[3], a3.x, q0); fma4(acc2[3], a3.y, q1); fma4(acc2[3], a3.z, q2); fma4(acc2[3], a3.w, q3);
  }
  __syncthreads();   // chunk-0 reads done
  *(float4*)&sm[W2S_OFF + tid * 4]         = st0;
  *(float4*)&sm[W2S_OFF + (tid + 256) * 4] = st1;
  *(float4*)&sm[W2S_OFF + (tid + 512) * 4] = w2a;
  *(float4*)&sm[W2S_OFF + (tid + 768) * 4] = w2b;
  __syncthreads();
  #pragma unroll 4
  for (int k4 = 16; k4 < 32; ++k4) {         // k 64..127
    float4 a0 = *(const float4*)&sm[H1S_OFF + (rt2 * 4 + 0) * H1S_P + k4 * 4];
    float4 a1 = *(const float4*)&sm[H1S_OFF + (rt2 * 4 + 1) * H1S_P + k4 * 4];
    float4 a2 = *(const float4*)&sm[H1S_OFF + (rt2 * 4 + 2) * H1S_P + k4 * 4];
    float4 a3 = *(const float4*)&sm[H1S_OFF + (rt2 * 4 + 3) * H1S_P + k4 * 4];
    float4 q0 = *(const float4*)&sm[W2S_OFF + ((k4 - 16) * 4 + 0) * H2_ + ct2 * 4];
    float4 q1 = *(const float4*)&sm[W2S_OFF + ((k4 - 16) * 4 + 1) * H2_ + ct2 * 4];
    float4 q2 = *(const float4*)&sm[W2S_OFF + ((k4 - 16) * 4 + 2) * H2_ + ct2 * 4];
    float4 q3 = *(const float4*)&sm[W2S_OFF + ((k4 - 16) * 4 + 3) * H2_ + ct2 * 4];
    fma4(acc2[0], a0.x, q0); fma4(acc2[0], a0.y, q1); fma4(acc2[0], a0.z, q2); fma4(acc2[0], a0.w, q3);
    fma4(acc2[1], a1.x, q0); fma4(acc2[1], a1.y, q1); fma4(acc2[1], a1.z, q2); fma4(acc2[1], a1.w, q3);
    fma4(acc2[2], a2.x, q0); fma4(acc2[2], a2.y, q1); fma4(acc2[2], a2.z, q2); fma4(acc2[2], a2.w, q3);
    fma4(acc2[3], a3.x, q0); fma4(acc2[3], a3.y, q1); fma4(acc2[3], a3.z, q2); fma4(acc2[3], a3.w, q3);
  }

  // ---- ReLU+b2 (regs); GEMM3 partials; butterfly over 16 col-groups ----
  float4 L[4];
  {
    #pragma unroll
    for (int r = 0; r < 4; ++r) {
      float4 h = acc2[r];
      h.x = fmaxf(h.x + b2v.x, 0.f); h.y = fmaxf(h.y + b2v.y, 0.f);
      h.z = fmaxf(h.z + b2v.z, 0.f); h.w = fmaxf(h.w + b2v.w, 0.f);
      float4 t = make_float4(0.f, 0.f, 0.f, 0.f);
      fma4(t, h.x, w30); fma4(t, h.y, w31); fma4(t, h.z, w32); fma4(t, h.w, w33);
      L[r] = t;
    }
  }
  #pragma unroll
  for (int d = 1; d < 16; d <<= 1) {
    #pragma unroll
    for (int r = 0; r < 4; ++r) {
      L[r].x += __shfl_xor(L[r].x, d);
      L[r].y += __shfl_xor(L[r].y, d);
      L[r].z += __shfl_xor(L[r].z, d);
      L[r].w += __shfl_xor(L[r].w, d);
    }
  }

  // ---- softmax + dom/conf: lane ct2 (0..3) handles row rt2*4 + ct2 ----
  if (ct2 < 4) {
    float4 Lv = L[ct2];
    const int grow = row0 + rt2 * 4 + ct2;
    Lv.x += b3v.x; Lv.y += b3v.y; Lv.z += b3v.z; Lv.w += b3v.w;
    float mx = fmaxf(fmaxf(Lv.x, Lv.y), fmaxf(Lv.z, Lv.w));
    float e0 = expf(Lv.x - mx), e1 = expf(Lv.y - mx), e2 = expf(Lv.z - mx), e3 = expf(Lv.w - mx);
    float inv = 1.f / ((e0 + e1) + (e2 + e3));
    float p0 = e0 * inv, p1 = e1 * inv, p2 = e2 * inv, p3 = e3 * inv;
    *(float4*)&out[PROBS_OFF + (size_t)grow * 4] = make_float4(p0, p1, p2, p3);
    int dom = 0; float pm = p0;
    if (p1 > pm) { pm = p1; dom = 1; }
    if (p2 > pm) { pm = p2; dom = 2; }
    if (p3 > pm) { pm = p3; dom = 3; }
    out[MI_OFF + grow] = (float)dom;   // park dom for kernel 2
    out[MC_OFF + grow] = pm;           // park conf for kernel 2
  }
}

// ---- kernel 2: per-batch-row segmentation + segment means ----
__global__ __launch_bounds__(1024, 1) void seg_kernel(
    const float* __restrict__ inten, float* __restrict__ out)
{
  __shared__ float scnt[T_], ssi[T_], ssc[T_];
  __shared__ int wtot[16], wexcl[16];
  const int tid = threadIdx.x;
  const int lane = tid & 63, wid = tid >> 6;
  const size_t base = (size_t)blockIdx.x * T_;
  const float* tsS = out + TS_OFF;
  float* segO = out + SEG_OFF;
  float* miO  = out + MI_OFF;
  float* mcO  = out + MC_OFF;
  const int t4 = tid * 4;

  float4 dv = *(const float4*)&miO[base + t4];        // dom (as float)
  float4 tv = *(const float4*)&tsS[base + t4];        // transition scores
  float4 iv = *(const float4*)&inten[base + t4];      // intensity
  float4 cv = *(const float4*)&mcO[base + t4];        // confidence
  float pd = (tid == 0) ? 0.f : miO[base + t4 - 1];

  for (int i = tid; i < T_; i += 1024) { scnt[i] = 0.f; ssi[i] = 0.f; ssc[i] = 0.f; }

  int c0 = (t4 == 0) ? 0 : (((dv.x != pd)   || (tv.x > 0.7f)) ? 1 : 0);
  int c1 = ((dv.y != dv.x) || (tv.y > 0.7f)) ? 1 : 0;
  int c2 = ((dv.z != dv.y) || (tv.z > 0.7f)) ? 1 : 0;
  int c3 = ((dv.w != dv.z) || (tv.w > 0.7f)) ? 1 : 0;
  int l0 = c0, l1 = c0 + c1, l2 = l1 + c2, l3 = l2 + c3;
  const int tsum = l3;

  // wave-inclusive scan of per-thread sums
  int v = tsum;
  #pragma unroll
  for (int d = 1; d < 64; d <<= 1) {
    int o = __shfl_up(v, (unsigned)d);
    if (lane >= d) v += o;
  }
  if (lane == 63) wtot[wid] = v;
  __syncthreads();
  if (tid < 16) {
    int x = wtot[tid];
    int xx = x;
    #pragma unroll
    for (int d = 1; d < 16; d <<= 1) {
      int o = __shfl_up(xx, (unsigned)d);
      if (tid >= d) xx += o;
    }
    wexcl[tid] = xx - x;   // exclusive wave offset
  }
  __syncthreads();
  const int texcl = wexcl[wid] + (v - tsum);
  const int s0 = texcl + l0, s1 = texcl + l1, s2 = texcl + l2, s3 = texcl + l3;

  // merged LDS atomics for segment sums
  {
    int cur = s0; float aI = iv.x, aC = cv.x, aN = 1.f;
    if (s1 == cur) { aI += iv.y; aC += cv.y; aN += 1.f; }
    else { atomicAdd(&ssi[cur], aI); atomicAdd(&ssc[cur], aC); atomicAdd(&scnt[cur], aN);
           cur = s1; aI = iv.y; aC = cv.y; aN = 1.f; }
    if (s2 == cur) { aI += iv.z; aC += cv.z; aN += 1.f; }
    else { atomicAdd(&ssi[cur], aI); atomicAdd(&ssc[cur], aC); atomicAdd(&scnt[cur], aN);
           cur = s2; aI = iv.z; aC = cv.z; aN = 1.f; }
    if (s3 == cur) { aI += iv.w; aC += cv.w; aN += 1.f; }
    else { atomicAdd(&ssi[cur], aI); atomicAdd(&ssc[cur], aC); atomicAdd(&scnt[cur], aN);
           cur = s3; aI = iv.w; aC = cv.w; aN = 1.f; }
    atomicAdd(&ssi[cur], aI); atomicAdd(&ssc[cur], aC); atomicAdd(&scnt[cur], aN);
  }
  __syncthreads();

  float n0 = scnt[s0], n1 = scnt[s1], n2 = scnt[s2], n3 = scnt[s3];
  float4 m4, q4, g4;
  m4.x = ssi[s0] / n0; m4.y = ssi[s1] / n1; m4.z = ssi[s2] / n2; m4.w = ssi[s3] / n3;
  q4.x = ssc[s0] / n0; q4.y = ssc[s1] / n1; q4.z = ssc[s2] / n2; q4.w = ssc[s3] / n3;
  g4.x = (float)s0; g4.y = (float)s1; g4.z = (float)s2; g4.w = (float)s3;
  *(float4*)&segO[base + t4] = g4;
  *(float4*)&miO[base + t4]  = m4;
  *(float4*)&mcO[base + t4]  = q4;
}

extern "C" void kernel_launch(void* const* d_in, const int* in_sizes, int n_in,
                              void* d_out, int out_size, void* d_ws, size_t ws_size,
                              hipStream_t stream) {
  (void)in_sizes; (void)n_in; (void)out_size; (void)d_ws; (void)ws_size;
  const float* X   = (const float*)d_in[0];
  const float* INT = (const float*)d_in[1];
  const float* W1  = (const float*)d_in[2];
  const float* B1  = (const float*)d_in[3];
  const float* W2  = (const float*)d_in[4];
  const float* B2  = (const float*)d_in[5];
  const float* W3  = (const float*)d_in[6];
  const float* B3  = (const float*)d_in[7];
  const float* CW  = (const float*)d_in[8];
  const float* CB  = (const float*)d_in[9];
  float* out = (float*)d_out;

  hipLaunchKernelGGL(mlp_conv_kernel, dim3(R_ / TB), dim3(256), 0, stream,
                     X, W1, B1, W2, B2, W3, B3, CW, CB, out);
  hipLaunchKernelGGL(seg_kernel, dim3(B_), dim3(1024), 0, stream, INT, out);
}

// Round 13
// 248.140 us; speedup vs baseline: 2.0736x; 1.2522x over previous
//
#include <hip/hip_runtime.h>

#define B_ 32
#define T_ 4096
#define C_ 256
#define R_ (B_*T_)
#define H1_ 128
#define H2_ 64

#define TB 64   // timestep rows per block in kernel 1

// output layout (floats), concatenated in reference return order
#define PROBS_OFF 0
#define TS_OFF  (R_*4)
#define SEG_OFF (TS_OFF + R_)
#define MI_OFF  (SEG_OFF + R_)
#define MC_OFF  (MI_OFF + R_)

// LDS float layout, 12544 floats = 50.2 KB -> 3 blocks/CU (LDS-limited):
//   XS  [64][132] at 0     (one 128-ch K-half of the X tile; -> H1S later)
//   W1S [16][128] at 8448  (2048 f; -> W2S [64][64] 4096 f later)
#define XS_OFF  0
#define XS_P    132
#define H1S_OFF 0
#define H1S_P   132
#define W1S_OFF 8448
#define W2S_OFF 8448
#define SMEMF   12544

__device__ __forceinline__ void fma4(float4& a, float s, const float4& b) {
  a.x = fmaf(s, b.x, a.x); a.y = fmaf(s, b.y, a.y);
  a.z = fmaf(s, b.z, a.z); a.w = fmaf(s, b.w, a.w);
}

// conv partial over one 16-channel slice of one K-half, one row-half
#define CONVPART(hh, khalf, svar)                                                  \
  {                                                                                \
    const int rowi = (hh) * 32 + w * 8 + (l & 7);                                  \
    const int p_ = l >> 3;                                                         \
    const int grow = row0 + rowi;                                                  \
    const int tb = grow & (T_ - 1);                                                \
    _Pragma("unroll")                                                              \
    for (int cc = 0; cc < 4; ++cc) {                                               \
      const int cl = p_ * 16 + cc * 4;                                             \
      const int cabs = (khalf) * 128 + cl;                                         \
      float4 x0 = *(const float4*)&sm[XS_OFF + rowi * XS_P + cl];                  \
      float4 xm, xp;                                                               \
      if (tb == 0)            xm = make_float4(0.f, 0.f, 0.f, 0.f);                \
      else if (rowi >= 1)     xm = *(const float4*)&sm[XS_OFF + (rowi - 1) * XS_P + cl]; \
      else                    xm = *(const float4*)&X[(size_t)(grow - 1) * C_ + cabs];   \
      if (tb == T_ - 1)       xp = make_float4(0.f, 0.f, 0.f, 0.f);                \
      else if (rowi + 1 < TB) xp = *(const float4*)&sm[XS_OFF + (rowi + 1) * XS_P + cl]; \
      else                    xp = *(const float4*)&X[(size_t)(grow + 1) * C_ + cabs];   \
      float4 wa = *(const float4*)&CW[cabs * 3 + 0];                               \
      float4 wb = *(const float4*)&CW[cabs * 3 + 4];                               \
      float4 wc = *(const float4*)&CW[cabs * 3 + 8];                               \
      svar += xm.x * wa.x + x0.x * wa.y + xp.x * wa.z;                             \
      svar += xm.y * wa.w + x0.y * wb.x + xp.y * wb.y;                             \
      svar += xm.z * wb.z + x0.z * wb.w + xp.z * wc.x;                             \
      svar += xm.w * wc.y + x0.w * wc.z + xp.w * wc.w;                             \
    }                                                                              \
  }

__global__ __launch_bounds__(256, 4) void mlp_conv_kernel(
    const float* __restrict__ X, const float* __restrict__ W1, const float* __restrict__ b1,
    const float* __restrict__ W2, const float* __restrict__ b2,
    const float* __restrict__ W3, const float* __restrict__ b3,
    const float* __restrict__ CW, const float* __restrict__ CB,
    float* __restrict__ out)
{
  __shared__ float sm[SMEMF];
  const int tid  = threadIdx.x;
  const int l    = tid & 63;
  const int w    = tid >> 6;
  const int row0 = blockIdx.x * TB;

  // ---- W1 chunk 0 (16 k-rows) prefetch into regs ----
  float4 st0 = ((const float4*)W1)[tid];
  float4 st1 = ((const float4*)W1)[tid + 256];
  float4 w2a = make_float4(0.f, 0.f, 0.f, 0.f), w2b = w2a;

  const int rt = tid >> 5, ct = tid & 31;   // 8 row-groups x 32 col-groups
  const int rb = rt * 8;
  float sA = 0.f, sB = 0.f;                 // conv partials (rows rowA/rowB)
  float4 acc[8];
  #pragma unroll
  for (int r = 0; r < 8; ++r) acc[r] = make_float4(0.f, 0.f, 0.f, 0.f);

  #pragma unroll
  for (int khalf = 0; khalf < 2; ++khalf) {
    // ---- stage X K-half tile (64 rows x 128 ch) into XS ----
    // (khalf=1 restage is safe: previous phase ended with __syncthreads)
    #pragma unroll
    for (int i2 = 0; i2 < 8; ++i2) {
      int g = tid + 256 * i2;          // 2048 f4: 64 rows x 32 f4
      int r = g >> 5, m = g & 31;
      float4 v = *(const float4*)&X[(size_t)(row0 + r) * C_ + khalf * 128 + m * 4];
      *(float4*)&sm[XS_OFF + r * XS_P + m * 4] = v;
    }
    __syncthreads();

    // ---- conv partials for this K-half (both row halves) ----
    CONVPART(0, khalf, sA)
    CONVPART(1, khalf, sB)
    if (khalf == 1) {   // finalize conv: reduce over 8 partials, sigmoid, store
      const int p_ = l >> 3;
      float s = sA;
      s += __shfl_xor(s, 8); s += __shfl_xor(s, 16); s += __shfl_xor(s, 32);
      if (p_ == 0) out[TS_OFF + row0 + w * 8 + (l & 7)] =
        1.f / (1.f + expf(-(s + CB[0])));
      s = sB;
      s += __shfl_xor(s, 8); s += __shfl_xor(s, 16); s += __shfl_xor(s, 32);
      if (p_ == 0) out[TS_OFF + row0 + 32 + w * 8 + (l & 7)] =
        1.f / (1.f + expf(-(s + CB[0])));
    }

    // ---- GEMM1 for this K-half: 8 chunks of 16 k-rows ----
    for (int kcl = 0; kcl < 8; ++kcl) {
      *(float4*)&sm[W1S_OFF + tid * 4]         = st0;
      *(float4*)&sm[W1S_OFF + (tid + 256) * 4] = st1;
      __syncthreads();
      const int kcg = khalf * 8 + kcl;
      if (kcg + 1 < 16) {   // prefetch next W1 chunk (hidden under compute)
        const float* wp = W1 + (size_t)(kcg + 1) * 2048;
        st0 = ((const float4*)wp)[tid];
        st1 = ((const float4*)wp)[tid + 256];
      } else {              // prefetch W2 chunk 0 (k-rows 0..63)
        st0 = ((const float4*)W2)[tid];
        st1 = ((const float4*)W2)[tid + 256];
        w2a = ((const float4*)W2)[tid + 512];
        w2b = ((const float4*)W2)[tid + 768];
      }
      #pragma unroll
      for (int k4 = 0; k4 < 4; ++k4) {
        const int colb = kcl * 16 + k4 * 4;
        float4 a0 = *(const float4*)&sm[XS_OFF + (rb + 0) * XS_P + colb];
        float4 a1 = *(const float4*)&sm[XS_OFF + (rb + 1) * XS_P + colb];
        float4 a2 = *(const float4*)&sm[XS_OFF + (rb + 2) * XS_P + colb];
        float4 a3 = *(const float4*)&sm[XS_OFF + (rb + 3) * XS_P + colb];
        float4 a4 = *(const float4*)&sm[XS_OFF + (rb + 4) * XS_P + colb];
        float4 a5 = *(const float4*)&sm[XS_OFF + (rb + 5) * XS_P + colb];
        float4 a6 = *(const float4*)&sm[XS_OFF + (rb + 6) * XS_P + colb];
        float4 a7 = *(const float4*)&sm[XS_OFF + (rb + 7) * XS_P + colb];
        float4 q0 = *(const float4*)&sm[W1S_OFF + (k4 * 4 + 0) * H1_ + ct * 4];
        float4 q1 = *(const float4*)&sm[W1S_OFF + (k4 * 4 + 1) * H1_ + ct * 4];
        float4 q2 = *(const float4*)&sm[W1S_OFF + (k4 * 4 + 2) * H1_ + ct * 4];
        float4 q3 = *(const float4*)&sm[W1S_OFF + (k4 * 4 + 3) * H1_ + ct * 4];
        fma4(acc[0], a0.x, q0); fma4(acc[0], a0.y, q1); fma4(acc[0], a0.z, q2); fma4(acc[0], a0.w, q3);
        fma4(acc[1], a1.x, q0); fma4(acc[1], a1.y, q1); fma4(acc[1], a1.z, q2); fma4(acc[1], a1.w, q3);
        fma4(acc[2], a2.x, q0); fma4(acc[2], a2.y, q1); fma4(acc[2], a2.z, q2); fma4(acc[2], a2.w, q3);
        fma4(acc[3], a3.x, q0); fma4(acc[3], a3.y, q1); fma4(acc[3], a3.z, q2); fma4(acc[3], a3.w, q3);
        fma4(acc[4], a4.x, q0); fma4(acc[4], a4.y, q1); fma4(acc[4], a4.z, q2); fma4(acc[4], a4.w, q3);
        fma4(acc[5], a5.x, q0); fma4(acc[5], a5.y, q1); fma4(acc[5], a5.z, q2); fma4(acc[5], a5.w, q3);
        fma4(acc[6], a6.x, q0); fma4(acc[6], a6.y, q1); fma4(acc[6], a6.z, q2); fma4(acc[6], a6.w, q3);
        fma4(acc[7], a7.x, q0); fma4(acc[7], a7.y, q1); fma4(acc[7], a7.z, q2); fma4(acc[7], a7.w, q3);
      }
      __syncthreads();   // all reads of this chunk (XS + W1S) done before next write
    }
  }

  // ---- epilogue regs (W3/b2/b3; latency hidden under H1 writes) ----
  const int rt2 = tid >> 4, ct2 = tid & 15;
  float4 w30 = ((const float4*)W3)[ct2 * 4 + 0];
  float4 w31 = ((const float4*)W3)[ct2 * 4 + 1];
  float4 w32 = ((const float4*)W3)[ct2 * 4 + 2];
  float4 w33 = ((const float4*)W3)[ct2 * 4 + 3];
  float4 b2v = ((const float4*)b2)[ct2];
  float4 b3v = *(const float4*)&b3[0];

  // ---- bias+relu -> H1S [64][132] (overlays XS, dead) ----
  {
    float4 bb = ((const float4*)b1)[ct];
    #pragma unroll
    for (int r = 0; r < 8; ++r) {
      float4 h = acc[r];
      h.x = fmaxf(h.x + bb.x, 0.f); h.y = fmaxf(h.y + bb.y, 0.f);
      h.z = fmaxf(h.z + bb.z, 0.f); h.w = fmaxf(h.w + bb.w, 0.f);
      *(float4*)&sm[H1S_OFF + (rb + r) * H1S_P + ct * 4] = h;
    }
  }
  // W2 chunk 0 -> W2S [64][64] (overlays W1S, dead)
  *(float4*)&sm[W2S_OFF + tid * 4]         = st0;
  *(float4*)&sm[W2S_OFF + (tid + 256) * 4] = st1;
  *(float4*)&sm[W2S_OFF + (tid + 512) * 4] = w2a;
  *(float4*)&sm[W2S_OFF + (tid + 768) * 4] = w2b;
  __syncthreads();

  // prefetch W2 chunk 1 (k-rows 64..127) — consumed after next barrier
  st0 = ((const float4*)W2)[tid + 1024];
  st1 = ((const float4*)W2)[tid + 1280];
  w2a = ((const float4*)W2)[tid + 1536];
  w2b = ((const float4*)W2)[tid + 1792];

  // ---- GEMM2: (64x128)@(128x64), 4x4 per thread; W2 in two 64-k chunks ----
  float4 acc2[4];
  #pragma unroll
  for (int j = 0; j < 4; ++j) acc2[j] = make_float4(0.f, 0.f, 0.f, 0.f);
  #pragma unroll 4
  for (int k4 = 0; k4 < 16; ++k4) {          // k 0..63
    float4 a0 = *(const float4*)&sm[H1S_OFF + (rt2 * 4 + 0) * H1S_P + k4 * 4];
    float4 a1 = *(const float4*)&sm[H1S_OFF + (rt2 * 4 + 1) * H1S_P + k4 * 4];
    float4 a2 = *(const float4*)&sm[H1S_OFF + (rt2 * 4 + 2) * H1S_P + k4 * 4];
    float4 a3 = *(const float4*)&sm[H1S_OFF + (rt2 * 4 + 3) * H1S_P + k4 * 4];
    float4 q0 = *(const float4*)&sm[W2S_OFF + (k4 * 4 + 0) * H2_ + ct2 * 4];
    float4 q1 = *(const float4*)&sm[W2S_OFF + (k4 * 4 + 1) * H2_ + ct2 * 4];
    float4 q2 = *(const float4*)&sm[W2S_OFF + (k4 * 4 + 2) * H2_ + ct2 * 4];
    float4 q3 = *(const float4*)&sm[W2S_OFF + (k4 * 4 + 3) * H2_ + ct2 * 4];
    fma4(acc2[0], a0.x, q0); fma4(acc2[0], a0.y, q1); fma4(acc2[0], a0.z, q2); fma4(acc2[0], a0.w, q3);
    fma4(acc2[1], a1.x, q0); fma4(acc2[1], a1.y, q1); fma4(acc2[1], a1.z, q2); fma4(acc2[1], a1.w, q3);
    fma4(acc2[2], a2.x, q0); fma4(acc2[2], a2.y, q1); fma4(acc2[2], a2.z, q2); fma4(acc2[2], a2.w, q3);
    fma4(acc2[3], a3.x, q0); fma4(acc2[3], a3.y, q1); fma4(acc2[3], a3.z, q2); fma4(acc2[3], a3.w, q3);
  }
  __syncthreads();   // chunk-0 reads done
  *(float4*)&sm[W2S_OFF + tid * 4]         = st0;
  *(float4*)&sm[W2S_OFF + (tid + 256) * 4] = st1;
  *(float4*)&sm[W2S_OFF + (tid + 512) * 4] = w2a;
  *(float4*)&sm[W2S_OFF + (tid + 768) * 4] = w2b;
  __syncthreads();
  #pragma unroll 4
  for (int k4 = 16; k4 < 32; ++k4) {         // k 64..127
    float4 a0 = *(const float4*)&sm[H1S_OFF + (rt2 * 4 + 0) * H1S_P + k4 * 4];
    float4 a1 = *(const float4*)&sm[H1S_OFF + (rt2 * 4 + 1) * H1S_P + k4 * 4];
    float4 a2 = *(const float4*)&sm[H1S_OFF + (rt2 * 4 + 2) * H1S_P + k4 * 4];
    float4 a3 = *(const float4*)&sm[H1S_OFF + (rt2 * 4 + 3) * H1S_P + k4 * 4];
    float4 q0 = *(const float4*)&sm[W2S_OFF + ((k4 - 16) * 4 + 0) * H2_ + ct2 * 4];
    float4 q1 = *(const float4*)&sm[W2S_OFF + ((k4 - 16) * 4 + 1) * H2_ + ct2 * 4];
    float4 q2 = *(const float4*)&sm[W2S_OFF + ((k4 - 16) * 4 + 2) * H2_ + ct2 * 4];
    float4 q3 = *(const float4*)&sm[W2S_OFF + ((k4 - 16) * 4 + 3) * H2_ + ct2 * 4];
    fma4(acc2[0], a0.x, q0); fma4(acc2[0], a0.y, q1); fma4(acc2[0], a0.z, q2); fma4(acc2[0], a0.w, q3);
    fma4(acc2[1], a1.x, q0); fma4(acc2[1], a1.y, q1); fma4(acc2[1], a1.z, q2); fma4(acc2[1], a1.w, q3);
    fma4(acc2[2], a2.x, q0); fma4(acc2[2], a2.y, q1); fma4(acc2[2], a2.z, q2); fma4(acc2[2], a2.w, q3);
    fma4(acc2[3], a3.x, q0); fma4(acc2[3], a3.y, q1); fma4(acc2[3], a3.z, q2); fma4(acc2[3], a3.w, q3);
  }

  // ---- ReLU+b2 (regs); GEMM3 partials; butterfly over 16 col-groups ----
  float4 L[4];
  {
    #pragma unroll
    for (int r = 0; r < 4; ++r) {
      float4 h = acc2[r];
      h.x = fmaxf(h.x + b2v.x, 0.f); h.y = fmaxf(h.y + b2v.y, 0.f);
      h.z = fmaxf(h.z + b2v.z, 0.f); h.w = fmaxf(h.w + b2v.w, 0.f);
      float4 t = make_float4(0.f, 0.f, 0.f, 0.f);
      fma4(t, h.x, w30); fma4(t, h.y, w31); fma4(t, h.z, w32); fma4(t, h.w, w33);
      L[r] = t;
    }
  }
  #pragma unroll
  for (int d = 1; d < 16; d <<= 1) {
    #pragma unroll
    for (int r = 0; r < 4; ++r) {
      L[r].x += __shfl_xor(L[r].x, d);
      L[r].y += __shfl_xor(L[r].y, d);
      L[r].z += __shfl_xor(L[r].z, d);
      L[r].w += __shfl_xor(L[r].w, d);
    }
  }

  // ---- softmax + dom/conf: lane ct2 (0..3) handles row rt2*4 + ct2 ----
  if (ct2 < 4) {
    float4 Lv = L[ct2];
    const int grow = row0 + rt2 * 4 + ct2;
    Lv.x += b3v.x; Lv.y += b3v.y; Lv.z += b3v.z; Lv.w += b3v.w;
    float mx = fmaxf(fmaxf(Lv.x, Lv.y), fmaxf(Lv.z, Lv.w));
    float e0 = expf(Lv.x - mx), e1 = expf(Lv.y - mx), e2 = expf(Lv.z - mx), e3 = expf(Lv.w - mx);
    float inv = 1.f / ((e0 + e1) + (e2 + e3));
    float p0 = e0 * inv, p1 = e1 * inv, p2 = e2 * inv, p3 = e3 * inv;
    *(float4*)&out[PROBS_OFF + (size_t)grow * 4] = make_float4(p0, p1, p2, p3);
    int dom = 0; float pm = p0;
    if (p1 > pm) { pm = p1; dom = 1; }
    if (p2 > pm) { pm = p2; dom = 2; }
    if (p3 > pm) { pm = p3; dom = 3; }
    out[MI_OFF + grow] = (float)dom;   // park dom for kernel 2
    out[MC_OFF + grow] = pm;           // park conf for kernel 2
  }
}

// ---- kernel 2: per-batch-row segmentation + segment means ----
__global__ __launch_bounds__(1024, 1) void seg_kernel(
    const float* __restrict__ inten, float* __restrict__ out)
{
  __shared__ float scnt[T_], ssi[T_], ssc[T_];
  __shared__ int wtot[16], wexcl[16];
  const int tid = threadIdx.x;
  const int lane = tid & 63, wid = tid >> 6;
  const size_t base = (size_t)blockIdx.x * T_;
  const float* tsS = out + TS_OFF;
  float* segO = out + SEG_OFF;
  float* miO  = out + MI_OFF;
  float* mcO  = out + MC_OFF;
  const int t4 = tid * 4;

  float4 dv = *(const float4*)&miO[base + t4];        // dom (as float)
  float4 tv = *(const float4*)&tsS[base + t4];        // transition scores
  float4 iv = *(const float4*)&inten[base + t4];      // intensity
  float4 cv = *(const float4*)&mcO[base + t4];        // confidence
  float pd = (tid == 0) ? 0.f : miO[base + t4 - 1];

  for (int i = tid; i < T_; i += 1024) { scnt[i] = 0.f; ssi[i] = 0.f; ssc[i] = 0.f; }

  int c0 = (t4 == 0) ? 0 : (((dv.x != pd)   || (tv.x > 0.7f)) ? 1 : 0);
  int c1 = ((dv.y != dv.x) || (tv.y > 0.7f)) ? 1 : 0;
  int c2 = ((dv.z != dv.y) || (tv.z > 0.7f)) ? 1 : 0;
  int c3 = ((dv.w != dv.z) || (tv.w > 0.7f)) ? 1 : 0;
  int l0 = c0, l1 = c0 + c1, l2 = l1 + c2, l3 = l2 + c3;
  const int tsum = l3;

  // wave-inclusive scan of per-thread sums
  int v = tsum;
  #pragma unroll
  for (int d = 1; d < 64; d <<= 1) {
    int o = __shfl_up(v, (unsigned)d);
    if (lane >= d) v += o;
  }
  if (lane == 63) wtot[wid] = v;
  __syncthreads();
  if (tid < 16) {
    int x = wtot[tid];
    int xx = x;
    #pragma unroll
    for (int d = 1; d < 16; d <<= 1) {
      int o = __shfl_up(xx, (unsigned)d);
      if (tid >= d) xx += o;
    }
    wexcl[tid] = xx - x;   // exclusive wave offset
  }
  __syncthreads();
  const int texcl = wexcl[wid] + (v - tsum);
  const int s0 = texcl + l0, s1 = texcl + l1, s2 = texcl + l2, s3 = texcl + l3;

  // merged LDS atomics for segment sums
  {
    int cur = s0; float aI = iv.x, aC = cv.x, aN = 1.f;
    if (s1 == cur) { aI += iv.y; aC += cv.y; aN += 1.f; }
    else { atomicAdd(&ssi[cur], aI); atomicAdd(&ssc[cur], aC); atomicAdd(&scnt[cur], aN);
           cur = s1; aI = iv.y; aC = cv.y; aN = 1.f; }
    if (s2 == cur) { aI += iv.z; aC += cv.z; aN += 1.f; }
    else { atomicAdd(&ssi[cur], aI); atomicAdd(&ssc[cur], aC); atomicAdd(&scnt[cur], aN);
           cur = s2; aI = iv.z; aC = cv.z; aN = 1.f; }
    if (s3 == cur) { aI += iv.w; aC += cv.w; aN += 1.f; }
    else { atomicAdd(&ssi[cur], aI); atomicAdd(&ssc[cur], aC); atomicAdd(&scnt[cur], aN);
           cur = s3; aI = iv.w; aC = cv.w; aN = 1.f; }
    atomicAdd(&ssi[cur], aI); atomicAdd(&ssc[cur], aC); atomicAdd(&scnt[cur], aN);
  }
  __syncthreads();

  float n0 = scnt[s0], n1 = scnt[s1], n2 = scnt[s2], n3 = scnt[s3];
  float4 m4, q4, g4;
  m4.x = ssi[s0] / n0; m4.y = ssi[s1] / n1; m4.z = ssi[s2] / n2; m4.w = ssi[s3] / n3;
  q4.x = ssc[s0] / n0; q4.y = ssc[s1] / n1; q4.z = ssc[s2] / n2; q4.w = ssc[s3] / n3;
  g4.x = (float)s0; g4.y = (float)s1; g4.z = (float)s2; g4.w = (float)s3;
  *(float4*)&segO[base + t4] = g4;
  *(float4*)&miO[base + t4]  = m4;
  *(float4*)&mcO[base + t4]  = q4;
}

extern "C" void kernel_launch(void* const* d_in, const int* in_sizes, int n_in,
                              void* d_out, int out_size, void* d_ws, size_t ws_size,
                              hipStream_t stream) {
  (void)in_sizes; (void)n_in; (void)out_size; (void)d_ws; (void)ws_size;
  const float* X   = (const float*)d_in[0];
  const float* INT = (const float*)d_in[1];
  const float* W1  = (const float*)d_in[2];
  const float* B1  = (const float*)d_in[3];
  const float* W2  = (const float*)d_in[4];
  const float* B2  = (const float*)d_in[5];
  const float* W3  = (const float*)d_in[6];
  const float* B3  = (const float*)d_in[7];
  const float* CW  = (const float*)d_in[8];
  const float* CB  = (const float*)d_in[9];
  float* out = (float*)d_out;

  hipLaunchKernelGGL(mlp_conv_kernel, dim3(R_ / TB), dim3(256), 0, stream,
                     X, W1, B1, W2, B2, W3, B3, CW, CB, out);
  hipLaunchKernelGGL(seg_kernel, dim3(B_), dim3(1024), 0, stream, INT, out);
}

// Round 14
// 202.827 us; speedup vs baseline: 2.5368x; 1.2234x over previous
//
#include <hip/hip_runtime.h>

#define B_ 32
#define T_ 4096
#define C_ 256
#define R_ (B_*T_)
#define H1_ 128
#define H2_ 64

#define TB 64   // timestep rows per block in kernel 1

// output layout (floats), concatenated in reference return order
#define PROBS_OFF 0
#define TS_OFF  (R_*4)
#define SEG_OFF (TS_OFF + R_)
#define MI_OFF  (SEG_OFF + R_)
#define MC_OFF  (MI_OFF + R_)

// LDS float layout, 18688 floats = 74.75 KB -> 2 blocks/CU:
//   Phase A (conv+GEMM1): XS [64][260] at 0 (16640 f),
//                         W1 dbuf: B0 [8][128] at 16640, B1 [8][128] at 17664
//   Phase B (GEMM2+):     H1S [64][132] at 0 (8448 f), W2S [128][64] at 8448 (8192 f)
#define XS_OFF  0
#define XS_P    260
#define H1S_OFF 0
#define H1S_P   132
#define W2S_OFF 8448
#define W1B0    16640
#define W1B1    17664
#define SMEMF   18688

__device__ __forceinline__ void fma4(float4& a, float s, const float4& b) {
  a.x = fmaf(s, b.x, a.x); a.y = fmaf(s, b.y, a.y);
  a.z = fmaf(s, b.z, a.z); a.w = fmaf(s, b.w, a.w);
}

// one 8-k-row chunk of GEMM1 from W1 LDS buffer BOFF, X cols CB..CB+7
#define G1CHUNK(BOFF, CB)                                                      \
  _Pragma("unroll")                                                            \
  for (int k4 = 0; k4 < 2; ++k4) {                                            \
    const int colb = (CB) + k4 * 4;                                           \
    float4 a0 = *(const float4*)&sm[XS_OFF + (rb + 0) * XS_P + colb];         \
    float4 a1 = *(const float4*)&sm[XS_OFF + (rb + 1) * XS_P + colb];         \
    float4 a2 = *(const float4*)&sm[XS_OFF + (rb + 2) * XS_P + colb];         \
    float4 a3 = *(const float4*)&sm[XS_OFF + (rb + 3) * XS_P + colb];         \
    float4 a4 = *(const float4*)&sm[XS_OFF + (rb + 4) * XS_P + colb];         \
    float4 a5 = *(const float4*)&sm[XS_OFF + (rb + 5) * XS_P + colb];         \
    float4 a6 = *(const float4*)&sm[XS_OFF + (rb + 6) * XS_P + colb];         \
    float4 a7 = *(const float4*)&sm[XS_OFF + (rb + 7) * XS_P + colb];         \
    float4 q0 = *(const float4*)&sm[(BOFF) + (k4 * 4 + 0) * H1_ + ct * 4];    \
    float4 q1 = *(const float4*)&sm[(BOFF) + (k4 * 4 + 1) * H1_ + ct * 4];    \
    float4 q2 = *(const float4*)&sm[(BOFF) + (k4 * 4 + 2) * H1_ + ct * 4];    \
    float4 q3 = *(const float4*)&sm[(BOFF) + (k4 * 4 + 3) * H1_ + ct * 4];    \
    fma4(acc[0], a0.x, q0); fma4(acc[0], a0.y, q1); fma4(acc[0], a0.z, q2); fma4(acc[0], a0.w, q3); \
    fma4(acc[1], a1.x, q0); fma4(acc[1], a1.y, q1); fma4(acc[1], a1.z, q2); fma4(acc[1], a1.w, q3); \
    fma4(acc[2], a2.x, q0); fma4(acc[2], a2.y, q1); fma4(acc[2], a2.z, q2); fma4(acc[2], a2.w, q3); \
    fma4(acc[3], a3.x, q0); fma4(acc[3], a3.y, q1); fma4(acc[3], a3.z, q2); fma4(acc[3], a3.w, q3); \
    fma4(acc[4], a4.x, q0); fma4(acc[4], a4.y, q1); fma4(acc[4], a4.z, q2); fma4(acc[4], a4.w, q3); \
    fma4(acc[5], a5.x, q0); fma4(acc[5], a5.y, q1); fma4(acc[5], a5.z, q2); fma4(acc[5], a5.w, q3); \
    fma4(acc[6], a6.x, q0); fma4(acc[6], a6.y, q1); fma4(acc[6], a6.z, q2); fma4(acc[6], a6.w, q3); \
    fma4(acc[7], a7.x, q0); fma4(acc[7], a7.y, q1); fma4(acc[7], a7.z, q2); fma4(acc[7], a7.w, q3); \
  }

__global__ __launch_bounds__(256, 2) void mlp_conv_kernel(
    const float* __restrict__ X, const float* __restrict__ W1, const float* __restrict__ b1,
    const float* __restrict__ W2, const float* __restrict__ b2,
    const float* __restrict__ W3, const float* __restrict__ b3,
    const float* __restrict__ CW, const float* __restrict__ CB,
    float* __restrict__ out)
{
  __shared__ float sm[SMEMF];
  const int tid  = threadIdx.x;
  const int l    = tid & 63;
  const int w    = tid >> 6;
  const int row0 = blockIdx.x * TB;

  // ---- W1 chunk 0 (8 k-rows = 256 f4) prefetch into reg ----
  float4 st = ((const float4*)W1)[tid];

  // ---- stage X tile (64 rows x 256) into padded LDS ----
  #pragma unroll
  for (int i2 = 0; i2 < 16; ++i2) {
    int g = tid + 256 * i2;          // f4 index: 64*64 = 4096 total
    int r = g >> 6, m = g & 63;
    float4 v = *(const float4*)&X[(size_t)(row0 + r) * C_ + m * 4];
    *(float4*)&sm[XS_OFF + r * XS_P + m * 4] = v;
  }
  __syncthreads();

  // ---- write W1 chunk 0 -> buf0; issue chunk 1 load (covered by conv) ----
  *(float4*)&sm[W1B0 + tid * 4] = st;
  st = ((const float4*)W1)[256 + tid];

  // ---- conv1d (C->1, k=3, SAME over T) + sigmoid -> transition_scores ----
  // identical per-row arithmetic to R8 (bit-identical ts), two 32-row halves
  #pragma unroll
  for (int half = 0; half < 2; ++half) {
    const int rowi = half * 32 + w * 8 + (l & 7);
    const int p = l >> 3;                        // 0..7
    const int grow = row0 + rowi;
    const int tb = grow & (T_ - 1);              // t within its batch row
    float s = 0.f;
    #pragma unroll
    for (int cc = 0; cc < 8; ++cc) {
      const int c = p * 32 + cc * 4;
      float4 x0 = *(const float4*)&sm[XS_OFF + rowi * XS_P + c];
      float4 xm, xp;
      if (tb == 0)             xm = make_float4(0.f, 0.f, 0.f, 0.f);
      else if (rowi >= 1)      xm = *(const float4*)&sm[XS_OFF + (rowi - 1) * XS_P + c];
      else                     xm = *(const float4*)&X[(size_t)(grow - 1) * C_ + c];
      if (tb == T_ - 1)        xp = make_float4(0.f, 0.f, 0.f, 0.f);
      else if (rowi + 1 < TB)  xp = *(const float4*)&sm[XS_OFF + (rowi + 1) * XS_P + c];
      else                     xp = *(const float4*)&X[(size_t)(grow + 1) * C_ + c];
      float4 wa = *(const float4*)&CW[c * 3 + 0];
      float4 wb = *(const float4*)&CW[c * 3 + 4];
      float4 wc = *(const float4*)&CW[c * 3 + 8];
      s += xm.x * wa.x + x0.x * wa.y + xp.x * wa.z;
      s += xm.y * wa.w + x0.y * wb.x + xp.y * wb.y;
      s += xm.z * wb.z + x0.z * wb.w + xp.z * wc.x;
      s += xm.w * wc.y + x0.w * wc.z + xp.w * wc.w;
    }
    s += __shfl_xor(s, 8);
    s += __shfl_xor(s, 16);
    s += __shfl_xor(s, 32);
    if (p == 0) out[TS_OFF + grow] = 1.f / (1.f + expf(-(s + CB[0])));
  }
  __syncthreads();   // buf0 visible; conv XS reads done

  // ---- GEMM1: (64x256)@(256x128), 8x4 per thread.
  //      A: X tile LDS (broadcast b128). B: W1 in 8-row chunks, double-buffered:
  //      write chunk c+1 during compute of chunk c; one barrier per chunk. ----
  const int rt = tid >> 5, ct = tid & 31;   // 8 row-groups x 32 col-groups
  const int rb = rt * 8;
  float4 acc[8];
  #pragma unroll
  for (int r = 0; r < 8; ++r) acc[r] = make_float4(0.f, 0.f, 0.f, 0.f);

  #pragma unroll 1
  for (int c = 0; c < 32; c += 2) {
    // entry invariant: buf0 = chunk c (fenced), st = chunk c+1 data
    G1CHUNK(W1B0, c * 8)
    *(float4*)&sm[W1B1 + tid * 4] = st;               // chunk c+1 -> buf1
    if (c + 2 < 32) st = ((const float4*)W1)[(c + 2) * 256 + tid];
    __syncthreads();
    G1CHUNK(W1B1, c * 8 + 8)
    if (c + 2 < 32) {
      *(float4*)&sm[W1B0 + tid * 4] = st;             // chunk c+2 -> buf0
      st = ((const float4*)W1)[(c + 3) * 256 + tid];  // c+3 <= 31 here
    }
    __syncthreads();
  }

  // ---- epilogue staging: W2 (8 f4) + W3/b2/b3 loads (hidden under H1 writes) ----
  const int rt2 = tid >> 4, ct2 = tid & 15;
  float4 w2q[8];
  #pragma unroll
  for (int i = 0; i < 8; ++i) w2q[i] = ((const float4*)W2)[tid + 256 * i];
  float4 w30 = ((const float4*)W3)[ct2 * 4 + 0];
  float4 w31 = ((const float4*)W3)[ct2 * 4 + 1];
  float4 w32 = ((const float4*)W3)[ct2 * 4 + 2];
  float4 w33 = ((const float4*)W3)[ct2 * 4 + 3];
  float4 b2v = ((const float4*)b2)[ct2];
  float4 b3v = *(const float4*)&b3[0];

  // ---- bias+relu -> H1S [64][132] (overlays XS; XS dead after final barrier) ----
  {
    float4 bb = ((const float4*)b1)[ct];
    #pragma unroll
    for (int r = 0; r < 8; ++r) {
      float4 h = acc[r];
      h.x = fmaxf(h.x + bb.x, 0.f); h.y = fmaxf(h.y + bb.y, 0.f);
      h.z = fmaxf(h.z + bb.z, 0.f); h.w = fmaxf(h.w + bb.w, 0.f);
      *(float4*)&sm[H1S_OFF + (rb + r) * H1S_P + ct * 4] = h;
    }
  }
  // W2 -> LDS linear [128][64] (overlays upper XS region)
  #pragma unroll
  for (int i = 0; i < 8; ++i)
    *(float4*)&sm[W2S_OFF + (tid + 256 * i) * 4] = w2q[i];
  __syncthreads();

  // ---- GEMM2: (64x128)@(128x64), 4x4 per thread, both operands LDS ----
  float4 acc2[4];
  #pragma unroll
  for (int j = 0; j < 4; ++j) acc2[j] = make_float4(0.f, 0.f, 0.f, 0.f);
  #pragma unroll 4
  for (int k4 = 0; k4 < 32; ++k4) {
    float4 a0 = *(const float4*)&sm[H1S_OFF + (rt2 * 4 + 0) * H1S_P + k4 * 4];
    float4 a1 = *(const float4*)&sm[H1S_OFF + (rt2 * 4 + 1) * H1S_P + k4 * 4];
    float4 a2 = *(const float4*)&sm[H1S_OFF + (rt2 * 4 + 2) * H1S_P + k4 * 4];
    float4 a3 = *(const float4*)&sm[H1S_OFF + (rt2 * 4 + 3) * H1S_P + k4 * 4];
    float4 q0 = *(const float4*)&sm[W2S_OFF + (k4 * 4 + 0) * H2_ + ct2 * 4];
    float4 q1 = *(const float4*)&sm[W2S_OFF + (k4 * 4 + 1) * H2_ + ct2 * 4];
    float4 q2 = *(const float4*)&sm[W2S_OFF + (k4 * 4 + 2) * H2_ + ct2 * 4];
    float4 q3 = *(const float4*)&sm[W2S_OFF + (k4 * 4 + 3) * H2_ + ct2 * 4];
    fma4(acc2[0], a0.x, q0); fma4(acc2[0], a0.y, q1); fma4(acc2[0], a0.z, q2); fma4(acc2[0], a0.w, q3);
    fma4(acc2[1], a1.x, q0); fma4(acc2[1], a1.y, q1); fma4(acc2[1], a1.z, q2); fma4(acc2[1], a1.w, q3);
    fma4(acc2[2], a2.x, q0); fma4(acc2[2], a2.y, q1); fma4(acc2[2], a2.z, q2); fma4(acc2[2], a2.w, q3);
    fma4(acc2[3], a3.x, q0); fma4(acc2[3], a3.y, q1); fma4(acc2[3], a3.z, q2); fma4(acc2[3], a3.w, q3);
  }

  // ---- ReLU+b2 (regs); GEMM3 partials; butterfly over 16 col-groups ----
  float4 L[4];
  {
    #pragma unroll
    for (int r = 0; r < 4; ++r) {
      float4 h = acc2[r];
      h.x = fmaxf(h.x + b2v.x, 0.f); h.y = fmaxf(h.y + b2v.y, 0.f);
      h.z = fmaxf(h.z + b2v.z, 0.f); h.w = fmaxf(h.w + b2v.w, 0.f);
      float4 t = make_float4(0.f, 0.f, 0.f, 0.f);
      fma4(t, h.x, w30); fma4(t, h.y, w31); fma4(t, h.z, w32); fma4(t, h.w, w33);
      L[r] = t;
    }
  }
  #pragma unroll
  for (int d = 1; d < 16; d <<= 1) {
    #pragma unroll
    for (int r = 0; r < 4; ++r) {
      L[r].x += __shfl_xor(L[r].x, d);
      L[r].y += __shfl_xor(L[r].y, d);
      L[r].z += __shfl_xor(L[r].z, d);
      L[r].w += __shfl_xor(L[r].w, d);
    }
  }

  // ---- softmax + dom/conf: lane ct2 (0..3) handles row rt2*4 + ct2 ----
  if (ct2 < 4) {
    float4 Lv = L[ct2];
    const int grow = row0 + rt2 * 4 + ct2;
    Lv.x += b3v.x; Lv.y += b3v.y; Lv.z += b3v.z; Lv.w += b3v.w;
    float mx = fmaxf(fmaxf(Lv.x, Lv.y), fmaxf(Lv.z, Lv.w));
    float e0 = expf(Lv.x - mx), e1 = expf(Lv.y - mx), e2 = expf(Lv.z - mx), e3 = expf(Lv.w - mx);
    float inv = 1.f / ((e0 + e1) + (e2 + e3));
    float p0 = e0 * inv, p1 = e1 * inv, p2 = e2 * inv, p3 = e3 * inv;
    *(float4*)&out[PROBS_OFF + (size_t)grow * 4] = make_float4(p0, p1, p2, p3);
    int dom = 0; float pm = p0;
    if (p1 > pm) { pm = p1; dom = 1; }
    if (p2 > pm) { pm = p2; dom = 2; }
    if (p3 > pm) { pm = p3; dom = 3; }
    out[MI_OFF + grow] = (float)dom;   // park dom for kernel 2
    out[MC_OFF + grow] = pm;           // park conf for kernel 2
  }
}

// ---- kernel 2: per-batch-row segmentation + segment means ----
__global__ __launch_bounds__(1024, 1) void seg_kernel(
    const float* __restrict__ inten, float* __restrict__ out)
{
  __shared__ float scnt[T_], ssi[T_], ssc[T_];
  __shared__ int wtot[16], wexcl[16];
  const int tid = threadIdx.x;
  const int lane = tid & 63, wid = tid >> 6;
  const size_t base = (size_t)blockIdx.x * T_;
  const float* tsS = out + TS_OFF;
  float* segO = out + SEG_OFF;
  float* miO  = out + MI_OFF;
  float* mcO  = out + MC_OFF;
  const int t4 = tid * 4;

  float4 dv = *(const float4*)&miO[base + t4];        // dom (as float)
  float4 tv = *(const float4*)&tsS[base + t4];        // transition scores
  float4 iv = *(const float4*)&inten[base + t4];      // intensity
  float4 cv = *(const float4*)&mcO[base + t4];        // confidence
  float pd = (tid == 0) ? 0.f : miO[base + t4 - 1];

  for (int i = tid; i < T_; i += 1024) { scnt[i] = 0.f; ssi[i] = 0.f; ssc[i] = 0.f; }

  int c0 = (t4 == 0) ? 0 : (((dv.x != pd)   || (tv.x > 0.7f)) ? 1 : 0);
  int c1 = ((dv.y != dv.x) || (tv.y > 0.7f)) ? 1 : 0;
  int c2 = ((dv.z != dv.y) || (tv.z > 0.7f)) ? 1 : 0;
  int c3 = ((dv.w != dv.z) || (tv.w > 0.7f)) ? 1 : 0;
  int l0 = c0, l1 = c0 + c1, l2 = l1 + c2, l3 = l2 + c3;
  const int tsum = l3;

  // wave-inclusive scan of per-thread sums
  int v = tsum;
  #pragma unroll
  for (int d = 1; d < 64; d <<= 1) {
    int o = __shfl_up(v, (unsigned)d);
    if (lane >= d) v += o;
  }
  if (lane == 63) wtot[wid] = v;
  __syncthreads();
  if (tid < 16) {
    int x = wtot[tid];
    int xx = x;
    #pragma unroll
    for (int d = 1; d < 16; d <<= 1) {
      int o = __shfl_up(xx, (unsigned)d);
      if (tid >= d) xx += o;
    }
    wexcl[tid] = xx - x;   // exclusive wave offset
  }
  __syncthreads();
  const int texcl = wexcl[wid] + (v - tsum);
  const int s0 = texcl + l0, s1 = texcl + l1, s2 = texcl + l2, s3 = texcl + l3;

  // merged LDS atomics for segment sums
  {
    int cur = s0; float aI = iv.x, aC = cv.x, aN = 1.f;
    if (s1 == cur) { aI += iv.y; aC += cv.y; aN += 1.f; }
    else { atomicAdd(&ssi[cur], aI); atomicAdd(&ssc[cur], aC); atomicAdd(&scnt[cur], aN);
           cur = s1; aI = iv.y; aC = cv.y; aN = 1.f; }
    if (s2 == cur) { aI += iv.z; aC += cv.z; aN += 1.f; }
    else { atomicAdd(&ssi[cur], aI); atomicAdd(&ssc[cur], aC); atomicAdd(&scnt[cur], aN);
           cur = s2; aI = iv.z; aC = cv.z; aN = 1.f; }
    if (s3 == cur) { aI += iv.w; aC += cv.w; aN += 1.f; }
    else { atomicAdd(&ssi[cur], aI); atomicAdd(&ssc[cur], aC); atomicAdd(&scnt[cur], aN);
           cur = s3; aI = iv.w; aC = cv.w; aN = 1.f; }
    atomicAdd(&ssi[cur], aI); atomicAdd(&ssc[cur], aC); atomicAdd(&scnt[cur], aN);
  }
  __syncthreads();

  float n0 = scnt[s0], n1 = scnt[s1], n2 = scnt[s2], n3 = scnt[s3];
  float4 m4, q4, g4;
  m4.x = ssi[s0] / n0; m4.y = ssi[s1] / n1; m4.z = ssi[s2] / n2; m4.w = ssi[s3] / n3;
  q4.x = ssc[s0] / n0; q4.y = ssc[s1] / n1; q4.z = ssc[s2] / n2; q4.w = ssc[s3] / n3;
  g4.x = (float)s0; g4.y = (float)s1; g4.z = (float)s2; g4.w = (float)s3;
  *(float4*)&segO[base + t4] = g4;
  *(float4*)&miO[base + t4]  = m4;
  *(float4*)&mcO[base + t4]  = q4;
}

extern "C" void kernel_launch(void* const* d_in, const int* in_sizes, int n_in,
                              void* d_out, int out_size, void* d_ws, size_t ws_size,
                              hipStream_t stream) {
  (void)in_sizes; (void)n_in; (void)out_size; (void)d_ws; (void)ws_size;
  const float* X   = (const float*)d_in[0];
  const float* INT = (const float*)d_in[1];
  const float* W1  = (const float*)d_in[2];
  const float* B1  = (const float*)d_in[3];
  const float* W2  = (const float*)d_in[4];
  const float* B2  = (const float*)d_in[5];
  const float* W3  = (const float*)d_in[6];
  const float* B3  = (const float*)d_in[7];
  const float* CW  = (const float*)d_in[8];
  const float* CB  = (const float*)d_in[9];
  float* out = (float*)d_out;

  hipLaunchKernelGGL(mlp_conv_kernel, dim3(R_ / TB), dim3(256), 0, stream,
                     X, W1, B1, W2, B2, W3, B3, CW, CB, out);
  hipLaunchKernelGGL(seg_kernel, dim3(B_), dim3(1024), 0, stream, INT, out);
}

// Round 15
// 186.142 us; speedup vs baseline: 2.7642x; 1.0896x over previous
//
#include <hip/hip_runtime.h>

#define B_ 32
#define T_ 4096
#define C_ 256
#define R_ (B_*T_)
#define H1_ 128
#define H2_ 64

#define TB 64   // timestep rows per block in kernel 1

// output layout (floats), concatenated in reference return order
#define PROBS_OFF 0
#define TS_OFF  (R_*4)
#define SEG_OFF (TS_OFF + R_)
#define MI_OFF  (SEG_OFF + R_)
#define MC_OFF  (MI_OFF + R_)

// LDS float layout, 16640 floats = 66.56 KB -> 2 blocks/CU:
//   Phase A (conv+GEMM1): XS [64][260] (16640 f) — read-only after staging
//   Phase B (GEMM2+):     H1S [64][132] at 0 (8448 f) + W2S [128][64] at 8448 (8192 f)
#define XS_OFF  0
#define XS_P    260
#define H1S_OFF 0
#define H1S_P   132
#define W2S_OFF 8448
#define SMEMF   16640

__device__ __forceinline__ void fma4(float4& a, float s, const float4& b) {
  a.x = fmaf(s, b.x, a.x); a.y = fmaf(s, b.y, a.y);
  a.z = fmaf(s, b.z, a.z); a.w = fmaf(s, b.w, a.w);
}

__global__ __launch_bounds__(256, 2) void mlp_conv_kernel(
    const float* __restrict__ X, const float* __restrict__ W1, const float* __restrict__ b1,
    const float* __restrict__ W2, const float* __restrict__ b2,
    const float* __restrict__ W3, const float* __restrict__ b3,
    const float* __restrict__ CW, const float* __restrict__ CB,
    float* __restrict__ out)
{
  __shared__ float sm[SMEMF];
  const int tid  = threadIdx.x;
  const int l    = tid & 63;
  const int w    = tid >> 6;
  const int row0 = blockIdx.x * TB;

  // ---- stage X tile (64 rows x 256) into padded LDS ----
  #pragma unroll
  for (int i2 = 0; i2 < 16; ++i2) {
    int g = tid + 256 * i2;          // f4 index: 64*64 = 4096 total
    int r = g >> 6, m = g & 63;
    float4 v = *(const float4*)&X[(size_t)(row0 + r) * C_ + m * 4];
    *(float4*)&sm[XS_OFF + r * XS_P + m * 4] = v;
  }
  __syncthreads();

  // ---- conv1d (C->1, k=3, SAME over T) + sigmoid -> transition_scores ----
  // identical per-row arithmetic to R8 (bit-identical ts), two 32-row halves
  #pragma unroll
  for (int half = 0; half < 2; ++half) {
    const int rowi = half * 32 + w * 8 + (l & 7);
    const int p = l >> 3;                        // 0..7
    const int grow = row0 + rowi;
    const int tb = grow & (T_ - 1);              // t within its batch row
    float s = 0.f;
    #pragma unroll
    for (int cc = 0; cc < 8; ++cc) {
      const int c = p * 32 + cc * 4;
      float4 x0 = *(const float4*)&sm[XS_OFF + rowi * XS_P + c];
      float4 xm, xp;
      if (tb == 0)             xm = make_float4(0.f, 0.f, 0.f, 0.f);
      else if (rowi >= 1)      xm = *(const float4*)&sm[XS_OFF + (rowi - 1) * XS_P + c];
      else                     xm = *(const float4*)&X[(size_t)(grow - 1) * C_ + c];
      if (tb == T_ - 1)        xp = make_float4(0.f, 0.f, 0.f, 0.f);
      else if (rowi + 1 < TB)  xp = *(const float4*)&sm[XS_OFF + (rowi + 1) * XS_P + c];
      else                     xp = *(const float4*)&X[(size_t)(grow + 1) * C_ + c];
      float4 wa = *(const float4*)&CW[c * 3 + 0];
      float4 wb = *(const float4*)&CW[c * 3 + 4];
      float4 wc = *(const float4*)&CW[c * 3 + 8];
      s += xm.x * wa.x + x0.x * wa.y + xp.x * wa.z;
      s += xm.y * wa.w + x0.y * wb.x + xp.y * wb.y;
      s += xm.z * wb.z + x0.z * wb.w + xp.z * wc.x;
      s += xm.w * wc.y + x0.w * wc.z + xp.w * wc.w;
    }
    s += __shfl_xor(s, 8);
    s += __shfl_xor(s, 16);
    s += __shfl_xor(s, 32);
    if (p == 0) out[TS_OFF + grow] = 1.f / (1.f + expf(-(s + CB[0])));
  }
  // NOTE: no barrier needed here — XS stays read-only through GEMM1.

  // ---- GEMM1: (64x256)@(256x128), 8x4 per thread, NO barriers.
  //      A: X tile in LDS (b128 broadcast reads).
  //      B: W1 from global (L2-hot, coalesced 512B/wave) with 1-deep
  //         register ping-pong prefetch (R4's proven GEMM2 pattern). ----
  const int rt = tid >> 5, ct = tid & 31;   // 8 row-groups x 32 col-groups
  const int rb = rt * 8;
  const float* wb1 = W1 + ct * 4;
  float4 acc[8];
  #pragma unroll
  for (int r = 0; r < 8; ++r) acc[r] = make_float4(0.f, 0.f, 0.f, 0.f);
  {
    float4 Bc0 = *(const float4*)&wb1[(size_t)0 * H1_];
    float4 Bc1 = *(const float4*)&wb1[(size_t)1 * H1_];
    float4 Bc2 = *(const float4*)&wb1[(size_t)2 * H1_];
    float4 Bc3 = *(const float4*)&wb1[(size_t)3 * H1_];
    #pragma unroll 2
    for (int k4 = 0; k4 < 64; ++k4) {
      const int kn = (k4 < 63) ? (k4 + 1) * 4 : 252;   // last iter reloads (discarded)
      float4 Bn0 = *(const float4*)&wb1[(size_t)(kn + 0) * H1_];
      float4 Bn1 = *(const float4*)&wb1[(size_t)(kn + 1) * H1_];
      float4 Bn2 = *(const float4*)&wb1[(size_t)(kn + 2) * H1_];
      float4 Bn3 = *(const float4*)&wb1[(size_t)(kn + 3) * H1_];
      const int kb = k4 * 4;
      float4 a0 = *(const float4*)&sm[XS_OFF + (rb + 0) * XS_P + kb];
      float4 a1 = *(const float4*)&sm[XS_OFF + (rb + 1) * XS_P + kb];
      float4 a2 = *(const float4*)&sm[XS_OFF + (rb + 2) * XS_P + kb];
      float4 a3 = *(const float4*)&sm[XS_OFF + (rb + 3) * XS_P + kb];
      float4 a4 = *(const float4*)&sm[XS_OFF + (rb + 4) * XS_P + kb];
      float4 a5 = *(const float4*)&sm[XS_OFF + (rb + 5) * XS_P + kb];
      float4 a6 = *(const float4*)&sm[XS_OFF + (rb + 6) * XS_P + kb];
      float4 a7 = *(const float4*)&sm[XS_OFF + (rb + 7) * XS_P + kb];
      fma4(acc[0], a0.x, Bc0); fma4(acc[0], a0.y, Bc1); fma4(acc[0], a0.z, Bc2); fma4(acc[0], a0.w, Bc3);
      fma4(acc[1], a1.x, Bc0); fma4(acc[1], a1.y, Bc1); fma4(acc[1], a1.z, Bc2); fma4(acc[1], a1.w, Bc3);
      fma4(acc[2], a2.x, Bc0); fma4(acc[2], a2.y, Bc1); fma4(acc[2], a2.z, Bc2); fma4(acc[2], a2.w, Bc3);
      fma4(acc[3], a3.x, Bc0); fma4(acc[3], a3.y, Bc1); fma4(acc[3], a3.z, Bc2); fma4(acc[3], a3.w, Bc3);
      fma4(acc[4], a4.x, Bc0); fma4(acc[4], a4.y, Bc1); fma4(acc[4], a4.z, Bc2); fma4(acc[4], a4.w, Bc3);
      fma4(acc[5], a5.x, Bc0); fma4(acc[5], a5.y, Bc1); fma4(acc[5], a5.z, Bc2); fma4(acc[5], a5.w, Bc3);
      fma4(acc[6], a6.x, Bc0); fma4(acc[6], a6.y, Bc1); fma4(acc[6], a6.z, Bc2); fma4(acc[6], a6.w, Bc3);
      fma4(acc[7], a7.x, Bc0); fma4(acc[7], a7.y, Bc1); fma4(acc[7], a7.z, Bc2); fma4(acc[7], a7.w, Bc3);
      Bc0 = Bn0; Bc1 = Bn1; Bc2 = Bn2; Bc3 = Bn3;
    }
  }

  // ---- epilogue staging: W2 (8 f4) + W3/b2/b3 loads issued BEFORE the
  //      barrier so their latency hides under other waves' GEMM1 tails ----
  const int rt2 = tid >> 4, ct2 = tid & 15;
  float4 w2q[8];
  #pragma unroll
  for (int i = 0; i < 8; ++i) w2q[i] = ((const float4*)W2)[tid + 256 * i];
  float4 w30 = ((const float4*)W3)[ct2 * 4 + 0];
  float4 w31 = ((const float4*)W3)[ct2 * 4 + 1];
  float4 w32 = ((const float4*)W3)[ct2 * 4 + 2];
  float4 w33 = ((const float4*)W3)[ct2 * 4 + 3];
  float4 b2v = ((const float4*)b2)[ct2];
  float4 b3v = *(const float4*)&b3[0];
  __syncthreads();   // ALL XS reads (conv + every wave's GEMM1) complete

  // ---- bias+relu -> H1S [64][132] (overlays XS) ; W2 -> W2S [128][64] ----
  {
    float4 bb = ((const float4*)b1)[ct];
    #pragma unroll
    for (int r = 0; r < 8; ++r) {
      float4 h = acc[r];
      h.x = fmaxf(h.x + bb.x, 0.f); h.y = fmaxf(h.y + bb.y, 0.f);
      h.z = fmaxf(h.z + bb.z, 0.f); h.w = fmaxf(h.w + bb.w, 0.f);
      *(float4*)&sm[H1S_OFF + (rb + r) * H1S_P + ct * 4] = h;
    }
  }
  #pragma unroll
  for (int i = 0; i < 8; ++i)
    *(float4*)&sm[W2S_OFF + (tid + 256 * i) * 4] = w2q[i];
  __syncthreads();

  // ---- GEMM2: (64x128)@(128x64), 4x4 per thread, both operands LDS ----
  float4 acc2[4];
  #pragma unroll
  for (int j = 0; j < 4; ++j) acc2[j] = make_float4(0.f, 0.f, 0.f, 0.f);
  #pragma unroll 4
  for (int k4 = 0; k4 < 32; ++k4) {
    float4 a0 = *(const float4*)&sm[H1S_OFF + (rt2 * 4 + 0) * H1S_P + k4 * 4];
    float4 a1 = *(const float4*)&sm[H1S_OFF + (rt2 * 4 + 1) * H1S_P + k4 * 4];
    float4 a2 = *(const float4*)&sm[H1S_OFF + (rt2 * 4 + 2) * H1S_P + k4 * 4];
    float4 a3 = *(const float4*)&sm[H1S_OFF + (rt2 * 4 + 3) * H1S_P + k4 * 4];
    float4 q0 = *(const float4*)&sm[W2S_OFF + (k4 * 4 + 0) * H2_ + ct2 * 4];
    float4 q1 = *(const float4*)&sm[W2S_OFF + (k4 * 4 + 1) * H2_ + ct2 * 4];
    float4 q2 = *(const float4*)&sm[W2S_OFF + (k4 * 4 + 2) * H2_ + ct2 * 4];
    float4 q3 = *(const float4*)&sm[W2S_OFF + (k4 * 4 + 3) * H2_ + ct2 * 4];
    fma4(acc2[0], a0.x, q0); fma4(acc2[0], a0.y, q1); fma4(acc2[0], a0.z, q2); fma4(acc2[0], a0.w, q3);
    fma4(acc2[1], a1.x, q0); fma4(acc2[1], a1.y, q1); fma4(acc2[1], a1.z, q2); fma4(acc2[1], a1.w, q3);
    fma4(acc2[2], a2.x, q0); fma4(acc2[2], a2.y, q1); fma4(acc2[2], a2.z, q2); fma4(acc2[2], a2.w, q3);
    fma4(acc2[3], a3.x, q0); fma4(acc2[3], a3.y, q1); fma4(acc2[3], a3.z, q2); fma4(acc2[3], a3.w, q3);
  }

  // ---- ReLU+b2 (regs); GEMM3 partials; butterfly over 16 col-groups ----
  float4 L[4];
  {
    #pragma unroll
    for (int r = 0; r < 4; ++r) {
      float4 h = acc2[r];
      h.x = fmaxf(h.x + b2v.x, 0.f); h.y = fmaxf(h.y + b2v.y, 0.f);
      h.z = fmaxf(h.z + b2v.z, 0.f); h.w = fmaxf(h.w + b2v.w, 0.f);
      float4 t = make_float4(0.f, 0.f, 0.f, 0.f);
      fma4(t, h.x, w30); fma4(t, h.y, w31); fma4(t, h.z, w32); fma4(t, h.w, w33);
      L[r] = t;
    }
  }
  #pragma unroll
  for (int d = 1; d < 16; d <<= 1) {
    #pragma unroll
    for (int r = 0; r < 4; ++r) {
      L[r].x += __shfl_xor(L[r].x, d);
      L[r].y += __shfl_xor(L[r].y, d);
      L[r].z += __shfl_xor(L[r].z, d);
      L[r].w += __shfl_xor(L[r].w, d);
    }
  }

  // ---- softmax + dom/conf: lane ct2 (0..3) handles row rt2*4 + ct2 ----
  if (ct2 < 4) {
    float4 Lv = L[ct2];
    const int grow = row0 + rt2 * 4 + ct2;
    Lv.x += b3v.x; Lv.y += b3v.y; Lv.z += b3v.z; Lv.w += b3v.w;
    float mx = fmaxf(fmaxf(Lv.x, Lv.y), fmaxf(Lv.z, Lv.w));
    float e0 = expf(Lv.x - mx), e1 = expf(Lv.y - mx), e2 = expf(Lv.z - mx), e3 = expf(Lv.w - mx);
    float inv = 1.f / ((e0 + e1) + (e2 + e3));
    float p0 = e0 * inv, p1 = e1 * inv, p2 = e2 * inv, p3 = e3 * inv;
    *(float4*)&out[PROBS_OFF + (size_t)grow * 4] = make_float4(p0, p1, p2, p3);
    int dom = 0; float pm = p0;
    if (p1 > pm) { pm = p1; dom = 1; }
    if (p2 > pm) { pm = p2; dom = 2; }
    if (p3 > pm) { pm = p3; dom = 3; }
    out[MI_OFF + grow] = (float)dom;   // park dom for kernel 2
    out[MC_OFF + grow] = pm;           // park conf for kernel 2
  }
}

// ---- kernel 2: per-batch-row segmentation + segment means ----
__global__ __launch_bounds__(1024, 1) void seg_kernel(
    const float* __restrict__ inten, float* __restrict__ out)
{
  __shared__ float scnt[T_], ssi[T_], ssc[T_];
  __shared__ int wtot[16], wexcl[16];
  const int tid = threadIdx.x;
  const int lane = tid & 63, wid = tid >> 6;
  const size_t base = (size_t)blockIdx.x * T_;
  const float* tsS = out + TS_OFF;
  float* segO = out + SEG_OFF;
  float* miO  = out + MI_OFF;
  float* mcO  = out + MC_OFF;
  const int t4 = tid * 4;

  float4 dv = *(const float4*)&miO[base + t4];        // dom (as float)
  float4 tv = *(const float4*)&tsS[base + t4];        // transition scores
  float4 iv = *(const float4*)&inten[base + t4];      // intensity
  float4 cv = *(const float4*)&mcO[base + t4];        // confidence
  float pd = (tid == 0) ? 0.f : miO[base + t4 - 1];

  for (int i = tid; i < T_; i += 1024) { scnt[i] = 0.f; ssi[i] = 0.f; ssc[i] = 0.f; }

  int c0 = (t4 == 0) ? 0 : (((dv.x != pd)   || (tv.x > 0.7f)) ? 1 : 0);
  int c1 = ((dv.y != dv.x) || (tv.y > 0.7f)) ? 1 : 0;
  int c2 = ((dv.z != dv.y) || (tv.z > 0.7f)) ? 1 : 0;
  int c3 = ((dv.w != dv.z) || (tv.w > 0.7f)) ? 1 : 0;
  int l0 = c0, l1 = c0 + c1, l2 = l1 + c2, l3 = l2 + c3;
  const int tsum = l3;

  // wave-inclusive scan of per-thread sums
  int v = tsum;
  #pragma unroll
  for (int d = 1; d < 64; d <<= 1) {
    int o = __shfl_up(v, (unsigned)d);
    if (lane >= d) v += o;
  }
  if (lane == 63) wtot[wid] = v;
  __syncthreads();
  if (tid < 16) {
    int x = wtot[tid];
    int xx = x;
    #pragma unroll
    for (int d = 1; d < 16; d <<= 1) {
      int o = __shfl_up(xx, (unsigned)d);
      if (tid >= d) xx += o;
    }
    wexcl[tid] = xx - x;   // exclusive wave offset
  }
  __syncthreads();
  const int texcl = wexcl[wid] + (v - tsum);
  const int s0 = texcl + l0, s1 = texcl + l1, s2 = texcl + l2, s3 = texcl + l3;

  // merged LDS atomics for segment sums
  {
    int cur = s0; float aI = iv.x, aC = cv.x, aN = 1.f;
    if (s1 == cur) { aI += iv.y; aC += cv.y; aN += 1.f; }
    else { atomicAdd(&ssi[cur], aI); atomicAdd(&ssc[cur], aC); atomicAdd(&scnt[cur], aN);
           cur = s1; aI = iv.y; aC = cv.y; aN = 1.f; }
    if (s2 == cur) { aI += iv.z; aC += cv.z; aN += 1.f; }
    else { atomicAdd(&ssi[cur], aI); atomicAdd(&ssc[cur], aC); atomicAdd(&scnt[cur], aN);
           cur = s2; aI = iv.z; aC = cv.z; aN = 1.f; }
    if (s3 == cur) { aI += iv.w; aC += cv.w; aN += 1.f; }
    else { atomicAdd(&ssi[cur], aI); atomicAdd(&ssc[cur], aC); atomicAdd(&scnt[cur], aN);
           cur = s3; aI = iv.w; aC = cv.w; aN = 1.f; }
    atomicAdd(&ssi[cur], aI); atomicAdd(&ssc[cur], aC); atomicAdd(&scnt[cur], aN);
  }
  __syncthreads();

  float n0 = scnt[s0], n1 = scnt[s1], n2 = scnt[s2], n3 = scnt[s3];
  float4 m4, q4, g4;
  m4.x = ssi[s0] / n0; m4.y = ssi[s1] / n1; m4.z = ssi[s2] / n2; m4.w = ssi[s3] / n3;
  q4.x = ssc[s0] / n0; q4.y = ssc[s1] / n1; q4.z = ssc[s2] / n2; q4.w = ssc[s3] / n3;
  g4.x = (float)s0; g4.y = (float)s1; g4.z = (float)s2; g4.w = (float)s3;
  *(float4*)&segO[base + t4] = g4;
  *(float4*)&miO[base + t4]  = m4;
  *(float4*)&mcO[base + t4]  = q4;
}

extern "C" void kernel_launch(void* const* d_in, const int* in_sizes, int n_in,
                              void* d_out, int out_size, void* d_ws, size_t ws_size,
                              hipStream_t stream) {
  (void)in_sizes; (void)n_in; (void)out_size; (void)d_ws; (void)ws_size;
  const float* X   = (const float*)d_in[0];
  const float* INT = (const float*)d_in[1];
  const float* W1  = (const float*)d_in[2];
  const float* B1  = (const float*)d_in[3];
  const float* W2  = (const float*)d_in[4];
  const float* B2  = (const float*)d_in[5];
  const float* W3  = (const float*)d_in[6];
  const float* B3  = (const float*)d_in[7];
  const float* CW  = (const float*)d_in[8];
  const float* CB  = (const float*)d_in[9];
  float* out = (float*)d_out;

  hipLaunchKernelGGL(mlp_conv_kernel, dim3(R_ / TB), dim3(256), 0, stream,
                     X, W1, B1, W2, B2, W3, B3, CW, CB, out);
  hipLaunchKernelGGL(seg_kernel, dim3(B_), dim3(1024), 0, stream, INT, out);
}